// Round 3
// baseline (484.594 us; speedup 1.0000x reference)
//
#include <hip/hip_runtime.h>
#include <hip/hip_bf16.h>

#define Bn 8
#define Ln 128
#define Hn 768
#define Pn 16
#define Dn 102
#define EPSF 1e-8f
#define NINF -1e30f

__device__ __forceinline__ float wred_sum(float v){
#pragma unroll
  for(int o=32;o>=1;o>>=1) v += __shfl_xor(v,o);
  return v;
}
__device__ __forceinline__ float wred_max(float v){
#pragma unroll
  for(int o=32;o>=1;o>>=1) v = fmaxf(v,__shfl_xor(v,o));
  return v;
}

// ---- workspace layout (float element offsets; total ~14.8 MB) ----
constexpr size_t SZ_MAT   = (size_t)Bn*Ln*Hn;            // 786432
constexpr size_t OFF_C1F  = 0;
constexpr size_t OFF_C2F  = OFF_C1F + SZ_MAT;
constexpr size_t OFF_C1T  = OFF_C2F + SZ_MAT;            // [b][h][i]
constexpr size_t OFF_C2T  = OFF_C1T + SZ_MAT;            // [b][h][j]
constexpr size_t OFF_COS  = OFF_C2T + SZ_MAT;            // B*L*L
constexpr size_t OFF_COST = OFF_COS + (size_t)Bn*Ln*Ln;
constexpr size_t OFF_N1   = OFF_COST + (size_t)Bn*Ln*Ln; // B*L
constexpr size_t OFF_N2   = OFF_N1 + (size_t)Bn*Ln;
constexpr size_t OFF_WN   = OFF_N2 + (size_t)Bn*Ln;      // 2*5*B*P*L
constexpr size_t OFF_W2T  = OFF_WN + (size_t)2*5*Bn*Pn*Ln; // 5*H*P [X][h][p]
constexpr size_t OFF_MVMAX  = OFF_W2T + (size_t)5*Hn*Pn; // 2*B*L*P
constexpr size_t OFF_MVMEAN = OFF_MVMAX + (size_t)2*Bn*Ln*Pn;
constexpr size_t OFF_LENS   = OFF_MVMEAN + (size_t)2*Bn*Ln*Pn; // 32 ints

__device__ __forceinline__ size_t wnIdx(int side,int X,int b,int p,int i){
  return ((((size_t)side*5 + X)*Bn + b)*Pn + p)*Ln + i;
}

// ---------------- k_prep: lengths + squared-weight tables ----------------
__global__ __launch_bounds__(256) void k_prep(
    const float* __restrict__ m1, const float* __restrict__ m2,
    const float* __restrict__ wff, const float* __restrict__ wfb,
    const float* __restrict__ wmp, const float* __restrict__ watt,
    const float* __restrict__ wmatt,
    float* __restrict__ W2T, int* __restrict__ lens){
  int t = threadIdx.x;
  if(blockIdx.x < 8){
    int b = blockIdx.x;
    __shared__ int cnt[2];
    if(t<2) cnt[t]=0;
    __syncthreads();
    if(t<Ln){
      if(m1[b*Ln+t]>0.5f) atomicAdd(&cnt[0],1);
      if(m2[b*Ln+t]>0.5f) atomicAdd(&cnt[1],1);
    }
    __syncthreads();
    if(t==0){
      lens[b]=cnt[0]; lens[8+b]=cnt[1];
      lens[16+b]=max(cnt[0]-1,0); lens[24+b]=max(cnt[1]-1,0);
    }
  } else {
    int idx = (blockIdx.x-8)*256 + t;     // < 5*768*16 = 61440
    const float* srcs[5] = {wff,wfb,wmp,watt,wmatt};
    int X = idx/(Pn*Hn);
    int r = idx%(Pn*Hn);
    int h = r/Pn, p = r%Pn;
    float w = srcs[X][p*Hn+h];
    W2T[idx] = w*w;                        // layout [X][h][p]
  }
}

// ---------------- k_rows: masked rows + norms + weighted norms ----------------
__global__ __launch_bounds__(256) void k_rows(
    const float* __restrict__ ctx1, const float* __restrict__ m1,
    const float* __restrict__ ctx2, const float* __restrict__ m2,
    const float* __restrict__ W2T,
    float* __restrict__ c1f, float* __restrict__ c2f,
    float* __restrict__ n1, float* __restrict__ n2, float* __restrict__ wn){
  int i = blockIdx.x, b = blockIdx.y, side = blockIdx.z;
  const float* ctx = side? ctx2 : ctx1;
  const float* msk = side? m2 : m1;
  float* dst = side? c2f : c1f;
  float* nD  = side? n2 : n1;
  int t = threadIdx.x, w=t>>6, l=t&63;
  float mk = msk[b*Ln+i];
  size_t base = ((size_t)(b*Ln+i))*Hn;
  float v[3];
#pragma unroll
  for(int k=0;k<3;k++){
    float x = ctx[base + t + 256*k] * mk;
    v[k]=x;
    dst[base + t + 256*k] = x;
  }
  __shared__ float red4[4];
  __shared__ float redW[64];
  float ss = v[0]*v[0]+v[1]*v[1]+v[2]*v[2];
  float sst = wred_sum(ss);
  if(l==0) red4[w]=sst;
  __syncthreads();
  if(t==0) nD[b*Ln+i] = sqrtf(fmaxf(red4[0]+red4[1]+red4[2]+red4[3],0.f));
  for(int X=0;X<5;++X){
    float acc[16];
#pragma unroll
    for(int p=0;p<16;p++) acc[p]=0.f;
#pragma unroll
    for(int k=0;k<3;k++){
      int h = t+256*k;
      float vv = v[k]*v[k];
      const float4* wq = (const float4*)(W2T + ((size_t)X*Hn + h)*Pn);
      float4 q0=wq[0],q1=wq[1],q2=wq[2],q3=wq[3];
      float wv[16]={q0.x,q0.y,q0.z,q0.w,q1.x,q1.y,q1.z,q1.w,
                    q2.x,q2.y,q2.z,q2.w,q3.x,q3.y,q3.z,q3.w};
#pragma unroll
      for(int p=0;p<16;p++) acc[p]=fmaf(wv[p],vv,acc[p]);
    }
    __syncthreads();
#pragma unroll
    for(int p=0;p<16;p++){
      float a = wred_sum(acc[p]);
      if(l==0) redW[w*16+p]=a;
    }
    __syncthreads();
    if(t<16){
      float s = redW[t]+redW[16+t]+redW[32+t]+redW[48+t];
      wn[wnIdx(side,X,b,t,i)] = s;
    }
    __syncthreads();
  }
}

// ---------------- fp32 transpose (32x32 tiles) ----------------
__global__ __launch_bounds__(256) void k_tr(
    const float* __restrict__ src, float* __restrict__ dst, int R, int C){
  __shared__ float tile[32][33];
  int b = blockIdx.z;
  int c0 = blockIdx.x*32, r0 = blockIdx.y*32;
  int tx = threadIdx.x & 31, ty = threadIdx.x >> 5;
  const float* s = src + (size_t)b*R*C;
  float* d = dst + (size_t)b*R*C;
#pragma unroll
  for(int k=0;k<4;k++){
    int r = r0 + ty + k*8;
    tile[ty+k*8][tx] = s[(size_t)r*C + c0 + tx];
  }
  __syncthreads();
#pragma unroll
  for(int k=0;k<4;k++){
    int c = c0 + ty + k*8;
    d[(size_t)c*R + r0 + tx] = tile[tx][ty+k*8];
  }
}

// ---------------- k_cos: pairwise cosine; writes cos AND cosT ----------------
__global__ __launch_bounds__(256) void k_cos(
    const float* __restrict__ c1f, const float* __restrict__ c2t,
    const float* __restrict__ n1, const float* __restrict__ n2,
    float* __restrict__ cosM, float* __restrict__ cosTr){
  int b = blockIdx.y;
  int i0 = blockIdx.x*4;
  int t = threadIdx.x;
  int j = t & 127, rp = t >> 7;
  __shared__ float sA[4][Hn];
  {
    const float* sp = c1f + ((size_t)(b*Ln+i0))*Hn;
    for(int idx=t; idx<4*Hn; idx+=256) sA[idx/Hn][idx%Hn] = sp[idx];
  }
  __syncthreads();
  int ra = i0 + rp*2, rb = ra+1;
  const float* ct = c2t + (size_t)b*Hn*Ln + j;
  float a0=0.f, a1=0.f;
#pragma unroll 4
  for(int h=0; h<Hn; ++h){
    float v = ct[(size_t)h*Ln];
    a0 = fmaf(sA[rp*2  ][h], v, a0);
    a1 = fmaf(sA[rp*2+1][h], v, a1);
  }
  float nj = fmaxf(n2[b*Ln+j], EPSF);
  float va = a0 / (fmaxf(n1[b*Ln+ra],EPSF)*nj);
  float vb = a1 / (fmaxf(n1[b*Ln+rb],EPSF)*nj);
  cosM[((size_t)(b*Ln+ra))*Ln + j] = va;
  cosM[((size_t)(b*Ln+rb))*Ln + j] = vb;
  cosTr[((size_t)(b*Ln+j))*Ln + ra] = va;
  cosTr[((size_t)(b*Ln+j))*Ln + rb] = vb;
}

// ---------------- k_mm: multi-perspective pairwise + masked max/mean ----------------
__global__ __launch_bounds__(256) void k_mm(
    const float* __restrict__ rowsF, const float* __restrict__ laneT,
    const float* __restrict__ W2mpT,
    const float* __restrict__ wnRow, const float* __restrict__ wnLane,
    const float* __restrict__ maskLane, const int* __restrict__ lenArr,
    float* __restrict__ mvmax, float* __restrict__ mvmean, int side){
  int b = blockIdx.y;
  int i0 = blockIdx.x*2;
  int t = threadIdx.x;
  int j = t & 127, ih = t >> 7;
  int i = i0 + ih;
  __shared__ float sA[2][Hn];
  {
    const float* rp = rowsF + ((size_t)(b*Ln+i0))*Hn;
    for(int idx=t; idx<2*Hn; idx+=256) sA[idx/Hn][idx%Hn] = rp[idx];
  }
  __syncthreads();
  const float* lt = laneT + (size_t)b*Hn*Ln + j;
  float acc[16];
#pragma unroll
  for(int p=0;p<16;p++) acc[p]=0.f;
  for(int h=0; h<Hn; ++h){
    float c2v = lt[(size_t)h*Ln];
    float prod = sA[ih][h]*c2v;
    const float4* wq = (const float4*)(W2mpT + (size_t)h*Pn);
    float4 q0=wq[0], q1=wq[1], q2=wq[2], q3=wq[3];
    float wv[16]={q0.x,q0.y,q0.z,q0.w,q1.x,q1.y,q1.z,q1.w,
                  q2.x,q2.y,q2.z,q2.w,q3.x,q3.y,q3.z,q3.w};
#pragma unroll
    for(int p=0;p<16;p++) acc[p]=fmaf(wv[p],prod,acc[p]);
  }
  bool valid = (maskLane[b*Ln+j] != 0.f);
  int len = min(max(lenArr[b],1),Ln);
  __shared__ float red[2][2][16][2];
  int w = t>>6, l = t&63, wp = w&1;
#pragma unroll
  for(int p=0;p<16;p++){
    float wr = fmaxf(wnRow[(b*Pn+p)*Ln + i],0.f);
    float wl = fmaxf(wnLane[(b*Pn+p)*Ln + j],0.f);
    float denom = fmaxf(sqrtf(wr)*sqrtf(wl), EPSF);
    float m = acc[p]/denom;
    float vmax = valid? m : NINF;
    float vsum = valid? m : 0.f;
    vmax = wred_max(vmax);
    vsum = wred_sum(vsum);
    if(l==0){ red[ih][wp][p][0]=vmax; red[ih][wp][p][1]=vsum; }
  }
  __syncthreads();
  if(t<64){
    int ih2 = t>>5, q = t&31, p = q&15, stat = q>>4;
    float A = red[ih2][0][p][stat], Bv = red[ih2][1][p][stat];
    size_t o = ((size_t)((side*Bn+b)*Ln + i0+ih2))*Pn + p;
    if(stat==0) mvmax[o] = fmaxf(A,Bv);
    else        mvmean[o] = (A+Bv)/(float)len;
  }
}

// ---------------- k_attfin: attention (regs) + full 102-feature rows ----------------
__global__ __launch_bounds__(256) void k_attfin(
    const float* __restrict__ c1f, const float* __restrict__ c2f,
    const float* __restrict__ cosM, const float* __restrict__ cosTr,
    const float* __restrict__ n1, const float* __restrict__ n2,
    const float* __restrict__ wn, const float* __restrict__ W2T,
    const float* __restrict__ mvmax, const float* __restrict__ mvmean,
    const int* __restrict__ lens,
    const float* __restrict__ m1, const float* __restrict__ m2,
    float* __restrict__ out){
  const int side = blockIdx.z, b = blockIdx.y, r0 = blockIdx.x*4;
  const int t = threadIdx.x, w = t>>6, l = t&63;
  const float* selfF  = side? c2f : c1f;
  const float* otherF = side? c1f : c2f;
  const float* nSelf  = side? n2 : n1;
  const float* nOther = side? n1 : n2;
  const float* mInner = side? m1 : m2;   // mask over inner index j
  const float* mSelfm = side? m2 : m1;
  int lenI = side? lens[b]    : lens[8+b];
  int lpO  = side? lens[16+b] : lens[24+b];
  lenI = min(max(lenI,1),Ln);
  lpO  = min(max(lpO,0),Ln-1);

  __shared__ float cS[4*Ln];
  __shared__ float mS[Ln];
  __shared__ float sV[4][Hn];
  __shared__ float red[34][4];
  __shared__ float fin[36];

  const float* crow = (side? cosTr : cosM) + ((size_t)(b*Ln+r0))*Ln;
  for(int idx=t; idx<4*Ln; idx+=256) cS[idx]=crow[idx];
  if(t<Ln) mS[t]=mInner[b*Ln+t];
  {
    const float* sp = selfF + ((size_t)(b*Ln+r0))*Hn;
    for(int idx=t; idx<4*Hn; idx+=256) sV[idx/Hn][idx%Hn] = sp[idx];
  }
  __syncthreads();

  // ---- attention accumulation over inner index jj ----
  float aS[4][3], aM[4][3];
#pragma unroll
  for(int rr=0;rr<4;rr++)
#pragma unroll
    for(int k=0;k<3;k++){ aS[rr][k]=0.f; aM[rr][k]=NINF; }
  const float* src = otherF + (size_t)b*Ln*Hn;
  for(int jj=0; jj<Ln; ++jj){
    const float* sp = src + (size_t)jj*Hn + t;
    float vk0 = sp[0];
    float vk1 = sp[256];
    float vk2 = sp[512];
    float msk = mS[jj];
    float c0=cS[jj], c1v=cS[Ln+jj], c2v=cS[2*Ln+jj], c3v=cS[3*Ln+jj];
    aS[0][0]=fmaf(vk0,c0 ,aS[0][0]); aS[0][1]=fmaf(vk1,c0 ,aS[0][1]); aS[0][2]=fmaf(vk2,c0 ,aS[0][2]);
    aS[1][0]=fmaf(vk0,c1v,aS[1][0]); aS[1][1]=fmaf(vk1,c1v,aS[1][1]); aS[1][2]=fmaf(vk2,c1v,aS[1][2]);
    aS[2][0]=fmaf(vk0,c2v,aS[2][0]); aS[2][1]=fmaf(vk1,c2v,aS[2][1]); aS[2][2]=fmaf(vk2,c2v,aS[2][2]);
    aS[3][0]=fmaf(vk0,c3v,aS[3][0]); aS[3][1]=fmaf(vk1,c3v,aS[3][1]); aS[3][2]=fmaf(vk2,c3v,aS[3][2]);
    if(msk!=0.f){
      aM[0][0]=fmaxf(aM[0][0],vk0*c0 ); aM[0][1]=fmaxf(aM[0][1],vk1*c0 ); aM[0][2]=fmaxf(aM[0][2],vk2*c0 );
      aM[1][0]=fmaxf(aM[1][0],vk0*c1v); aM[1][1]=fmaxf(aM[1][1],vk1*c1v); aM[1][2]=fmaxf(aM[1][2],vk2*c1v);
      aM[2][0]=fmaxf(aM[2][0],vk0*c2v); aM[2][1]=fmaxf(aM[2][1],vk1*c2v); aM[2][2]=fmaxf(aM[2][2],vk2*c2v);
      aM[3][0]=fmaxf(aM[3][0],vk0*c3v); aM[3][1]=fmaxf(aM[3][1],vk1*c3v); aM[3][2]=fmaxf(aM[3][2],vk2*c3v);
    }
  }

  // ---- softmax over h per row (att_mean).  Reference masks with -1e30
  // (FINITE), so fully-masked rows softmax to uniform 1/H. ----
  float smr[4];
#pragma unroll
  for(int rr=0;rr<4;rr++) smr[rr]=mSelfm[b*Ln+r0+rr];
#pragma unroll
  for(int rr=0;rr<4;rr++){
    float lm = fmaxf(fmaxf(aS[rr][0],aS[rr][1]),aS[rr][2]);
    lm = wred_max(lm);
    if(l==0) red[rr][w]=lm;
  }
  __syncthreads();
  float bm[4];
#pragma unroll
  for(int rr=0;rr<4;rr++) bm[rr]=fmaxf(fmaxf(red[rr][0],red[rr][1]),fmaxf(red[rr][2],red[rr][3]));
  __syncthreads();
  float ev[4][3];
#pragma unroll
  for(int rr=0;rr<4;rr++){
    float es=0.f;
#pragma unroll
    for(int k=0;k<3;k++){ ev[rr][k]=expf(aS[rr][k]-bm[rr]); es+=ev[rr][k]; }
    es = wred_sum(es);
    if(l==0) red[rr][w]=es;
  }
  __syncthreads();
#pragma unroll
  for(int rr=0;rr<4;rr++){
    float bs = red[rr][0]+red[rr][1]+red[rr][2]+red[rr][3];
    float inv = 1.f/fmaxf(bs,EPSF);
#pragma unroll
    for(int k=0;k<3;k++) aS[rr][k] = (smr[rr]!=0.f)? ev[rr][k]*inv : (1.f/(float)Hn);
  }
  __syncthreads();

  // ---- Phase A: cos row max/mean  +  Phase C: mv max/mean copy ----
  {
    float cmx[4], csm[4];
#pragma unroll
    for(int rr=0;rr<4;rr++){ cmx[rr]=NINF; csm[rr]=0.f; }
    if(t<Ln && mS[t]!=0.f){
#pragma unroll
      for(int rr=0;rr<4;rr++){ float c=cS[rr*Ln+t]; cmx[rr]=c; csm[rr]=c; }
    }
#pragma unroll
    for(int rr=0;rr<4;rr++){
      float a = wred_max(cmx[rr]);
      float s = wred_sum(csm[rr]);
      if(l==0){ red[rr][w]=a; red[8+rr][w]=s; }
    }
    __syncthreads();
    if(t<4){
      int rr=t;
      float M = fmaxf(fmaxf(red[rr][0],red[rr][1]),fmaxf(red[rr][2],red[rr][3]));
      float S = red[8+rr][0]+red[8+rr][1]+red[8+rr][2]+red[8+rr][3];
      float* op = out + ((size_t)((b*2+side)*Ln + r0+rr))*Dn;
      op[0] = M;
      op[1] = S/(float)lenI;
    }
    if(t>=64 && t<192){
      int q = t-64;
      int rr = q>>5, qq = q&31, p = qq&15;
      size_t o = ((size_t)((side*Bn+b)*Ln + r0+rr))*Pn + p;
      float* op = out + ((size_t)((b*2+side)*Ln + r0+rr))*Dn;
      if(qq<16) op[36+p] = mvmax[o];
      else      op[52+p] = mvmean[o];
    }
    __syncthreads();
  }

  // ---- Phase B: four mpm blocks per row ----
  float fv[3], blv[3];
  {
    const float* fp = otherF + ((size_t)(b*Ln+lpO))*Hn;
    const float* bp = otherF + ((size_t)(b*Ln))*Hn;
#pragma unroll
    for(int k=0;k<3;k++){ fv[k]=fp[t+256*k]; blv[k]=bp[t+256*k]; }
  }
  float nv1r[4];
#pragma unroll
  for(int rr=0;rr<4;rr++) nv1r[rr]=nSelf[b*Ln+r0+rr];

  const int Xids[4] = {0,1,3,4};
  const int offS[4] = {2,19,68,85};
  for(int mi=0; mi<4; ++mi){
    const int X = Xids[mi];
    const float* w2 = W2T + (size_t)X*Hn*Pn;
    float wv[3][16];
#pragma unroll
    for(int k=0;k<3;k++){
      const float4* wq = (const float4*)(w2 + (size_t)(t+256*k)*Pn);
      float4 q0=wq[0], q1=wq[1], q2=wq[2], q3=wq[3];
      wv[k][0]=q0.x; wv[k][1]=q0.y; wv[k][2]=q0.z; wv[k][3]=q0.w;
      wv[k][4]=q1.x; wv[k][5]=q1.y; wv[k][6]=q1.z; wv[k][7]=q1.w;
      wv[k][8]=q2.x; wv[k][9]=q2.y; wv[k][10]=q2.z; wv[k][11]=q2.w;
      wv[k][12]=q3.x; wv[k][13]=q3.y; wv[k][14]=q3.z; wv[k][15]=q3.w;
    }
    const bool dyn = (mi>=2);
    for(int rr=0; rr<4; ++rr){
      const int r = r0+rr;
      float v1k[3] = { sV[rr][t], sV[rr][t+256], sV[rr][t+512] };
      float bv[3];
#pragma unroll
      for(int k=0;k<3;k++)
        bv[k] = (mi==0)? fv[k] : (mi==1)? blv[k] : (mi==2)? aS[rr][k] : aM[rr][k];
      float s0=0.f, sn=0.f;
      float sw[16], snw[16];
#pragma unroll
      for(int p=0;p<16;p++){ sw[p]=0.f; snw[p]=0.f; }
#pragma unroll
      for(int k=0;k<3;k++){
        float pr = v1k[k]*bv[k];
        float bb = bv[k]*bv[k];
        s0 += pr; sn += bb;
#pragma unroll
        for(int p=0;p<16;p++){
          sw[p]=fmaf(wv[k][p],pr,sw[p]);
          if(dyn) snw[p]=fmaf(wv[k][p],bb,snw[p]);
        }
      }
      __syncthreads();    // previous iteration's fin/red readers done
      s0 = wred_sum(s0);
      if(dyn) sn = wred_sum(sn);
#pragma unroll
      for(int p=0;p<16;p++){
        sw[p]=wred_sum(sw[p]);
        if(dyn) snw[p]=wred_sum(snw[p]);
      }
      if(l==0){
        red[0][w]=s0; red[1][w]= dyn? sn : 0.f;
#pragma unroll
        for(int p=0;p<16;p++){ red[2+p][w]=sw[p]; red[18+p][w]= dyn? snw[p] : 0.f; }
      }
      __syncthreads();
      if(t<34) fin[t] = red[t][0]+red[t][1]+red[t][2]+red[t][3];
      __syncthreads();
      float* op = out + ((size_t)((b*2+side)*Ln + r))*Dn;
      if(t==0){
        float nb = dyn ? sqrtf(fmaxf(fin[1],0.f)) : nOther[b*Ln + (mi==0? lpO : 0)];
        float sng = fin[0]/(fmaxf(nv1r[rr],EPSF)*fmaxf(nb,EPSF));
        op[offS[mi]] = sng;
      }
      if(t<16){
        int p=t;
        float wa = fmaxf(wn[wnIdx(side,X,b,p,r)],0.f);
        float wb = dyn ? fmaxf(fin[18+p],0.f) : fmaxf(wn[wnIdx(1-side,X,b,p,(mi==0? lpO:0))],0.f);
        float mul = fin[2+p]/(fmaxf(sqrtf(wa),EPSF)*fmaxf(sqrtf(wb),EPSF));
        op[offS[mi]+1+p] = mul;
      }
    }
  }
}

extern "C" void kernel_launch(void* const* d_in, const int* in_sizes, int n_in,
                              void* d_out, int out_size, void* d_ws, size_t ws_size,
                              hipStream_t stream) {
  const float* ctx1 = (const float*)d_in[0];
  const float* m1   = (const float*)d_in[1];
  const float* ctx2 = (const float*)d_in[2];
  const float* m2   = (const float*)d_in[3];
  const float* wff  = (const float*)d_in[4];
  const float* wfb  = (const float*)d_in[5];
  const float* wmp  = (const float*)d_in[6];
  const float* watt = (const float*)d_in[7];
  const float* wmatt= (const float*)d_in[8];
  float* out = (float*)d_out;
  float* W = (float*)d_ws;
  int* lens = (int*)(W + OFF_LENS);

  k_prep<<<dim3(8 + (5*Pn*Hn)/256), 256, 0, stream>>>(m1,m2,wff,wfb,wmp,watt,wmatt,
      W+OFF_W2T, lens);
  k_rows<<<dim3(Ln,Bn,2), 256, 0, stream>>>(ctx1,m1,ctx2,m2, W+OFF_W2T,
      W+OFF_C1F, W+OFF_C2F, W+OFF_N1, W+OFF_N2, W+OFF_WN);
  k_tr<<<dim3(Hn/32, Ln/32, Bn), 256, 0, stream>>>(W+OFF_C1F, W+OFF_C1T, Ln, Hn);
  k_tr<<<dim3(Hn/32, Ln/32, Bn), 256, 0, stream>>>(W+OFF_C2F, W+OFF_C2T, Ln, Hn);
  k_cos<<<dim3(Ln/4, Bn), 256, 0, stream>>>(W+OFF_C1F, W+OFF_C2T, W+OFF_N1, W+OFF_N2,
      W+OFF_COS, W+OFF_COST);

  const size_t wnMP0 = (size_t)(0*5 + 2)*Bn*Pn*Ln;   // wn[side=0][X=MP]
  const size_t wnMP1 = (size_t)(1*5 + 2)*Bn*Pn*Ln;   // wn[side=1][X=MP]
  k_mm<<<dim3(Ln/2, Bn), 256, 0, stream>>>(W+OFF_C1F, W+OFF_C2T, W+OFF_W2T + (size_t)2*Hn*Pn,
      W+OFF_WN+wnMP0, W+OFF_WN+wnMP1, m2, lens+8, W+OFF_MVMAX, W+OFF_MVMEAN, 0);
  k_mm<<<dim3(Ln/2, Bn), 256, 0, stream>>>(W+OFF_C2F, W+OFF_C1T, W+OFF_W2T + (size_t)2*Hn*Pn,
      W+OFF_WN+wnMP1, W+OFF_WN+wnMP0, m1, lens+0, W+OFF_MVMAX, W+OFF_MVMEAN, 1);

  k_attfin<<<dim3(Ln/4, Bn, 2), 256, 0, stream>>>(W+OFF_C1F, W+OFF_C2F, W+OFF_COS, W+OFF_COST,
      W+OFF_N1, W+OFF_N2, W+OFF_WN, W+OFF_W2T, W+OFF_MVMAX, W+OFF_MVMEAN,
      lens, m1, m2, out);
}

// Round 4
// 381.816 us; speedup vs baseline: 1.2692x; 1.2692x over previous
//
#include <hip/hip_runtime.h>

#define Bn 8
#define Ln 128
#define Hn 768
#define Pn 16
#define Dn 102
#define EPSF 1e-8f
#define NINF -1e30f

__device__ __forceinline__ float wred_sum(float v){
#pragma unroll
  for(int o=32;o>=1;o>>=1) v += __shfl_xor(v,o);
  return v;
}
__device__ __forceinline__ float wred_max(float v){
#pragma unroll
  for(int o=32;o>=1;o>>=1) v = fmaxf(v,__shfl_xor(v,o));
  return v;
}

// ---- workspace layout (float element offsets; total ~8.5 MB) ----
constexpr size_t SZ_MAT   = (size_t)Bn*Ln*Hn;            // 786432
constexpr size_t OFF_C1F  = 0;
constexpr size_t OFF_C2F  = OFF_C1F + SZ_MAT;
constexpr size_t OFF_COS  = OFF_C2F + SZ_MAT;            // B*L*L
constexpr size_t OFF_COST = OFF_COS + (size_t)Bn*Ln*Ln;
constexpr size_t OFF_N1   = OFF_COST + (size_t)Bn*Ln*Ln; // B*L
constexpr size_t OFF_N2   = OFF_N1 + (size_t)Bn*Ln;
constexpr size_t OFF_WN   = OFF_N2 + (size_t)Bn*Ln;      // 2*5*B*P*L
constexpr size_t OFF_W2T  = OFF_WN + (size_t)2*5*Bn*Pn*Ln; // 5*H*P [X][h][p]
constexpr size_t OFF_MVMAX  = OFF_W2T + (size_t)5*Hn*Pn; // 2*B*L*P
constexpr size_t OFF_MVMEAN = OFF_MVMAX + (size_t)2*Bn*Ln*Pn;
constexpr size_t OFF_LENS   = OFF_MVMEAN + (size_t)2*Bn*Ln*Pn; // 32 ints

__device__ __forceinline__ size_t wnIdx(int side,int X,int b,int p,int i){
  return ((((size_t)side*5 + X)*Bn + b)*Pn + p)*Ln + i;
}

// ---------------- k_prep: lengths + squared-weight tables ----------------
__global__ __launch_bounds__(256) void k_prep(
    const float* __restrict__ m1, const float* __restrict__ m2,
    const float* __restrict__ wff, const float* __restrict__ wfb,
    const float* __restrict__ wmp, const float* __restrict__ watt,
    const float* __restrict__ wmatt,
    float* __restrict__ W2T, int* __restrict__ lens){
  int t = threadIdx.x;
  if(blockIdx.x < 8){
    int b = blockIdx.x;
    __shared__ int cnt[2];
    if(t<2) cnt[t]=0;
    __syncthreads();
    if(t<Ln){
      if(m1[b*Ln+t]>0.5f) atomicAdd(&cnt[0],1);
      if(m2[b*Ln+t]>0.5f) atomicAdd(&cnt[1],1);
    }
    __syncthreads();
    if(t==0){
      lens[b]=cnt[0]; lens[8+b]=cnt[1];
      lens[16+b]=max(cnt[0]-1,0); lens[24+b]=max(cnt[1]-1,0);
    }
  } else {
    int idx = (blockIdx.x-8)*256 + t;     // < 5*768*16 = 61440
    const float* srcs[5] = {wff,wfb,wmp,watt,wmatt};
    int X = idx/(Pn*Hn);
    int r = idx%(Pn*Hn);
    int h = r/Pn, p = r%Pn;
    float w = srcs[X][p*Hn+h];
    W2T[idx] = w*w;                        // layout [X][h][p]
  }
}

// ---------------- k_rows: masked rows + norms + weighted norms ----------------
__global__ __launch_bounds__(256) void k_rows(
    const float* __restrict__ ctx1, const float* __restrict__ m1,
    const float* __restrict__ ctx2, const float* __restrict__ m2,
    const float* __restrict__ W2T,
    float* __restrict__ c1f, float* __restrict__ c2f,
    float* __restrict__ n1, float* __restrict__ n2, float* __restrict__ wn){
  int i = blockIdx.x, b = blockIdx.y, side = blockIdx.z;
  const float* ctx = side? ctx2 : ctx1;
  const float* msk = side? m2 : m1;
  float* dst = side? c2f : c1f;
  float* nD  = side? n2 : n1;
  int t = threadIdx.x, w=t>>6, l=t&63;
  float mk = msk[b*Ln+i];
  size_t base = ((size_t)(b*Ln+i))*Hn;
  float v[3];
#pragma unroll
  for(int k=0;k<3;k++){
    float x = ctx[base + t + 256*k] * mk;
    v[k]=x;
    dst[base + t + 256*k] = x;
  }
  __shared__ float red4[4];
  __shared__ float redW[64];
  float ss = v[0]*v[0]+v[1]*v[1]+v[2]*v[2];
  float sst = wred_sum(ss);
  if(l==0) red4[w]=sst;
  __syncthreads();
  if(t==0) nD[b*Ln+i] = sqrtf(fmaxf(red4[0]+red4[1]+red4[2]+red4[3],0.f));
  for(int X=0;X<5;++X){
    float acc[16];
#pragma unroll
    for(int p=0;p<16;p++) acc[p]=0.f;
#pragma unroll
    for(int k=0;k<3;k++){
      int h = t+256*k;
      float vv = v[k]*v[k];
      const float4* wq = (const float4*)(W2T + ((size_t)X*Hn + h)*Pn);
      float4 q0=wq[0],q1=wq[1],q2=wq[2],q3=wq[3];
      float wv[16]={q0.x,q0.y,q0.z,q0.w,q1.x,q1.y,q1.z,q1.w,
                    q2.x,q2.y,q2.z,q2.w,q3.x,q3.y,q3.z,q3.w};
#pragma unroll
      for(int p=0;p<16;p++) acc[p]=fmaf(wv[p],vv,acc[p]);
    }
    __syncthreads();
#pragma unroll
    for(int p=0;p<16;p++){
      float a = wred_sum(acc[p]);
      if(l==0) redW[w*16+p]=a;
    }
    __syncthreads();
    if(t<16){
      float s = redW[t]+redW[16+t]+redW[32+t]+redW[48+t];
      wn[wnIdx(side,X,b,t,i)] = s;
    }
    __syncthreads();
  }
}

// ---------------- k_cos: pairwise cosine; writes cos AND cosT ----------------
// grid (Bn, Ln/4): blockIdx.x = b  (XCD-local: all blocks of b share an XCD's L2)
__global__ __launch_bounds__(256) void k_cos(
    const float* __restrict__ c1f, const float* __restrict__ c2f,
    const float* __restrict__ n1, const float* __restrict__ n2,
    float* __restrict__ cosM, float* __restrict__ cosTr){
  int b = blockIdx.x, i0 = blockIdx.y*4;
  int t = threadIdx.x, j = t&127, rp = t>>7;
  __shared__ float sA[4*Hn];
  __shared__ float sT[128][4];
  for(int idx=t; idx<4*Hn; idx+=256) sA[idx] = c1f[((size_t)(b*Ln+i0))*Hn + idx];
  __syncthreads();
  const float4* crow = (const float4*)(c2f + ((size_t)(b*Ln+j))*Hn);
  int ra = rp*2, rb = ra+1;   // local row idx 0..3
  float a0=0.f, a1=0.f;
#pragma unroll 4
  for(int hq=0; hq<Hn/4; ++hq){
    float4 v = crow[hq];
    int h = hq*4;
    a0 = fmaf(sA[ra*Hn+h  ], v.x, a0);
    a0 = fmaf(sA[ra*Hn+h+1], v.y, a0);
    a0 = fmaf(sA[ra*Hn+h+2], v.z, a0);
    a0 = fmaf(sA[ra*Hn+h+3], v.w, a0);
    a1 = fmaf(sA[rb*Hn+h  ], v.x, a1);
    a1 = fmaf(sA[rb*Hn+h+1], v.y, a1);
    a1 = fmaf(sA[rb*Hn+h+2], v.z, a1);
    a1 = fmaf(sA[rb*Hn+h+3], v.w, a1);
  }
  float nj = fmaxf(n2[b*Ln+j], EPSF);
  float va = a0 / (fmaxf(n1[b*Ln+i0+ra],EPSF)*nj);
  float vb = a1 / (fmaxf(n1[b*Ln+i0+rb],EPSF)*nj);
  cosM[((size_t)(b*Ln+i0+ra))*Ln + j] = va;
  cosM[((size_t)(b*Ln+i0+rb))*Ln + j] = vb;
  sT[j][ra]=va; sT[j][rb]=vb;
  __syncthreads();
  if(t<128){
    float4 o = *(const float4*)sT[t];
    *((float4*)(cosTr + ((size_t)(b*Ln+t))*Ln + i0)) = o;
  }
}

// ---------------- k_mm: both sides, LDS-broadcast W2, float4 B-rows ----------------
// grid (16, Ln/4): x = side*8+b  (XCD k serves (0,k) and (1,k): c1f[b]+c2f[b] L2-local)
__global__ __launch_bounds__(256) void k_mm(
    const float* __restrict__ c1f, const float* __restrict__ c2f,
    const float* __restrict__ W2mp, const float* __restrict__ WN,
    const float* __restrict__ m1, const float* __restrict__ m2,
    const int* __restrict__ lens,
    float* __restrict__ mvmax, float* __restrict__ mvmean){
  const int x = blockIdx.x, side = x>>3, b = x&7;
  const int i0 = blockIdx.y*4;
  const int t = threadIdx.x;
  const float* selfF = side? c2f : c1f;
  const float* laneF = side? c1f : c2f;
  const float* mlane = side? m1 : m2;
  int lenv = lens[side? b : 8+b];
  lenv = min(max(lenv,1),Ln);

  __shared__ float sW2[Hn*Pn];     // 48 KB
  __shared__ float sA[4*Hn];       // 12 KB
  __shared__ float redR[4][4][8][2];
  for(int idx=t; idx<Hn*Pn; idx+=256) sW2[idx]=W2mp[idx];
  for(int idx=t; idx<4*Hn;  idx+=256) sA[idx]=selfF[((size_t)(b*Ln+i0))*Hn + idx];
  __syncthreads();

  const int j = t&127, ph = t>>7;   // ph: p-half (wave-uniform)
  const float4* lrow4 = (const float4*)(laneF + ((size_t)(b*Ln+j))*Hn);
  float acc[4][8];
#pragma unroll
  for(int i=0;i<4;i++)
#pragma unroll
    for(int pp=0;pp<8;pp++) acc[i][pp]=0.f;

#pragma unroll 2
  for(int hq=0; hq<Hn/4; ++hq){
    float4 bq = lrow4[hq];
    int h4 = hq*4;
#pragma unroll
    for(int d=0; d<4; ++d){
      int h = h4+d;
      float bv = (d==0)? bq.x : (d==1)? bq.y : (d==2)? bq.z : bq.w;
      const float4* wrow = (const float4*)(sW2 + h*Pn + ph*8);
      float4 w0 = wrow[0], w1 = wrow[1];
      float wvv[8] = {w0.x,w0.y,w0.z,w0.w,w1.x,w1.y,w1.z,w1.w};
#pragma unroll
      for(int i=0;i<4;i++){
        float pr = sA[i*Hn+h]*bv;
#pragma unroll
        for(int pp=0;pp<8;pp++) acc[i][pp]=fmaf(wvv[pp],pr,acc[i][pp]);
      }
    }
  }

  const bool valid = (mlane[b*Ln+j]!=0.f);
  const int w = t>>6, l = t&63;
  float slane[8];
#pragma unroll
  for(int pp=0;pp<8;pp++)
    slane[pp] = sqrtf(fmaxf(WN[wnIdx(1-side,2,b,ph*8+pp,j)],0.f));
#pragma unroll
  for(int i=0;i<4;i++){
#pragma unroll
    for(int pp=0;pp<8;pp++){
      float sr = sqrtf(fmaxf(WN[wnIdx(side,2,b,ph*8+pp,i0+i)],0.f));
      float m = acc[i][pp]/fmaxf(sr*slane[pp],EPSF);
      float vmax = valid? m : NINF;
      float vsum = valid? m : 0.f;
      vmax = wred_max(vmax);
      vsum = wred_sum(vsum);
      if(l==0){ redR[w][i][pp][0]=vmax; redR[w][i][pp][1]=vsum; }
    }
  }
  __syncthreads();
  if(t<128){
    int st = t&1, pp = (t>>1)&7, ii = (t>>4)&3, p2 = (t>>6)&1;
    int p = p2*8+pp;
    float A = redR[2*p2][ii][pp][st], Bv = redR[2*p2+1][ii][pp][st];
    size_t o = ((size_t)((side*Bn+b)*Ln + i0+ii))*Pn + p;
    if(st==0) mvmax[o] = fmaxf(A,Bv);
    else      mvmean[o] = (A+Bv)/(float)lenv;
  }
}

// ---------------- k_attfin: attention (regs, dwordx3) + full 102-feature rows ----------------
// grid (16, Ln/4): x = side*8+b  (same XCD pairing as k_mm)
__global__ __launch_bounds__(256) void k_attfin(
    const float* __restrict__ c1f, const float* __restrict__ c2f,
    const float* __restrict__ cosM, const float* __restrict__ cosTr,
    const float* __restrict__ n1, const float* __restrict__ n2,
    const float* __restrict__ wn, const float* __restrict__ W2T,
    const float* __restrict__ mvmax, const float* __restrict__ mvmean,
    const int* __restrict__ lens,
    const float* __restrict__ m1, const float* __restrict__ m2,
    float* __restrict__ out){
  const int x = blockIdx.x, side = x>>3, b = x&7;
  const int r0 = blockIdx.y*4;
  const int t = threadIdx.x, w = t>>6, l = t&63;
  const float* selfF  = side? c2f : c1f;
  const float* otherF = side? c1f : c2f;
  const float* nSelf  = side? n2 : n1;
  const float* nOther = side? n1 : n2;
  const float* mInner = side? m1 : m2;
  const float* mSelfm = side? m2 : m1;
  int lenI = side? lens[b]    : lens[8+b];
  int lpO  = side? lens[16+b] : lens[24+b];
  lenI = min(max(lenI,1),Ln);
  lpO  = min(max(lpO,0),Ln-1);

  __shared__ float cS[4*Ln];
  __shared__ float mS[Ln];
  __shared__ float red[34][4];
  __shared__ float fin[36];

  const float* crow = (side? cosTr : cosM) + ((size_t)(b*Ln+r0))*Ln;
  for(int idx=t; idx<4*Ln; idx+=256) cS[idx]=crow[idx];
  if(t<Ln) mS[t]=mInner[b*Ln+t];

  // self rows (h = 3t..3t+2 mapping)
  float v1r[4][3];
#pragma unroll
  for(int rr=0;rr<4;rr++){
    float3 v = ((const float3*)(selfF + ((size_t)(b*Ln+r0+rr))*Hn))[t];
    v1r[rr][0]=v.x; v1r[rr][1]=v.y; v1r[rr][2]=v.z;
  }
  __syncthreads();

  // ---- attention accumulation over inner index jj ----
  float aS[4][3], aM[4][3];
#pragma unroll
  for(int rr=0;rr<4;rr++)
#pragma unroll
    for(int k=0;k<3;k++){ aS[rr][k]=0.f; aM[rr][k]=NINF; }
  const float* src = otherF + (size_t)b*Ln*Hn;
#pragma unroll 4
  for(int jj=0; jj<Ln; ++jj){
    float3 vk = ((const float3*)(src + (size_t)jj*Hn))[t];
    float vk0=vk.x, vk1=vk.y, vk2=vk.z;
    float msk = mS[jj];
    float c0=cS[jj], c1v=cS[Ln+jj], c2v=cS[2*Ln+jj], c3v=cS[3*Ln+jj];
    aS[0][0]=fmaf(vk0,c0 ,aS[0][0]); aS[0][1]=fmaf(vk1,c0 ,aS[0][1]); aS[0][2]=fmaf(vk2,c0 ,aS[0][2]);
    aS[1][0]=fmaf(vk0,c1v,aS[1][0]); aS[1][1]=fmaf(vk1,c1v,aS[1][1]); aS[1][2]=fmaf(vk2,c1v,aS[1][2]);
    aS[2][0]=fmaf(vk0,c2v,aS[2][0]); aS[2][1]=fmaf(vk1,c2v,aS[2][1]); aS[2][2]=fmaf(vk2,c2v,aS[2][2]);
    aS[3][0]=fmaf(vk0,c3v,aS[3][0]); aS[3][1]=fmaf(vk1,c3v,aS[3][1]); aS[3][2]=fmaf(vk2,c3v,aS[3][2]);
    if(msk!=0.f){
      aM[0][0]=fmaxf(aM[0][0],vk0*c0 ); aM[0][1]=fmaxf(aM[0][1],vk1*c0 ); aM[0][2]=fmaxf(aM[0][2],vk2*c0 );
      aM[1][0]=fmaxf(aM[1][0],vk0*c1v); aM[1][1]=fmaxf(aM[1][1],vk1*c1v); aM[1][2]=fmaxf(aM[1][2],vk2*c1v);
      aM[2][0]=fmaxf(aM[2][0],vk0*c2v); aM[2][1]=fmaxf(aM[2][1],vk1*c2v); aM[2][2]=fmaxf(aM[2][2],vk2*c2v);
      aM[3][0]=fmaxf(aM[3][0],vk0*c3v); aM[3][1]=fmaxf(aM[3][1],vk1*c3v); aM[3][2]=fmaxf(aM[3][2],vk2*c3v);
    }
  }

  // ---- softmax over h per row (att_mean); -1e30 masking => fully-masked rows → uniform ----
  float smr[4];
#pragma unroll
  for(int rr=0;rr<4;rr++) smr[rr]=mSelfm[b*Ln+r0+rr];
#pragma unroll
  for(int rr=0;rr<4;rr++){
    float lm = fmaxf(fmaxf(aS[rr][0],aS[rr][1]),aS[rr][2]);
    lm = wred_max(lm);
    if(l==0) red[rr][w]=lm;
  }
  __syncthreads();
  float bm[4];
#pragma unroll
  for(int rr=0;rr<4;rr++) bm[rr]=fmaxf(fmaxf(red[rr][0],red[rr][1]),fmaxf(red[rr][2],red[rr][3]));
  __syncthreads();
  float ev[4][3];
#pragma unroll
  for(int rr=0;rr<4;rr++){
    float es=0.f;
#pragma unroll
    for(int k=0;k<3;k++){ ev[rr][k]=expf(aS[rr][k]-bm[rr]); es+=ev[rr][k]; }
    es = wred_sum(es);
    if(l==0) red[rr][w]=es;
  }
  __syncthreads();
#pragma unroll
  for(int rr=0;rr<4;rr++){
    float bs = red[rr][0]+red[rr][1]+red[rr][2]+red[rr][3];
    float inv = 1.f/fmaxf(bs,EPSF);
#pragma unroll
    for(int k=0;k<3;k++) aS[rr][k] = (smr[rr]!=0.f)? ev[rr][k]*inv : (1.f/(float)Hn);
  }
  __syncthreads();

  // ---- Phase A: cos row max/mean  +  Phase C: mv max/mean copy ----
  {
    float cmx[4], csm[4];
#pragma unroll
    for(int rr=0;rr<4;rr++){ cmx[rr]=NINF; csm[rr]=0.f; }
    if(t<Ln && mS[t]!=0.f){
#pragma unroll
      for(int rr=0;rr<4;rr++){ float c=cS[rr*Ln+t]; cmx[rr]=c; csm[rr]=c; }
    }
#pragma unroll
    for(int rr=0;rr<4;rr++){
      float a = wred_max(cmx[rr]);
      float s = wred_sum(csm[rr]);
      if(l==0){ red[rr][w]=a; red[8+rr][w]=s; }
    }
    __syncthreads();
    if(t<4){
      int rr=t;
      float M = fmaxf(fmaxf(red[rr][0],red[rr][1]),fmaxf(red[rr][2],red[rr][3]));
      float S = red[8+rr][0]+red[8+rr][1]+red[8+rr][2]+red[8+rr][3];
      float* op = out + ((size_t)((b*2+side)*Ln + r0+rr))*Dn;
      op[0] = M;
      op[1] = S/(float)lenI;
    }
    if(t>=64 && t<192){
      int q = t-64;
      int rr = q>>5, qq = q&31, p = qq&15;
      size_t o = ((size_t)((side*Bn+b)*Ln + r0+rr))*Pn + p;
      float* op = out + ((size_t)((b*2+side)*Ln + r0+rr))*Dn;
      if(qq<16) op[36+p] = mvmax[o];
      else      op[52+p] = mvmean[o];
    }
    __syncthreads();
  }

  // ---- Phase B: four mpm blocks per row ----
  float fv[3], blv[3];
  {
    float3 f = ((const float3*)(otherF + ((size_t)(b*Ln+lpO))*Hn))[t];
    float3 g = ((const float3*)(otherF + ((size_t)(b*Ln))*Hn))[t];
    fv[0]=f.x; fv[1]=f.y; fv[2]=f.z;
    blv[0]=g.x; blv[1]=g.y; blv[2]=g.z;
  }
  float nv1r[4];
#pragma unroll
  for(int rr=0;rr<4;rr++) nv1r[rr]=nSelf[b*Ln+r0+rr];

  const int Xids[4] = {0,1,3,4};
  const int offS[4] = {2,19,68,85};
  for(int mi=0; mi<4; ++mi){
    const int X = Xids[mi];
    const float* w2 = W2T + (size_t)X*Hn*Pn;
    float wv[3][16];
#pragma unroll
    for(int k=0;k<3;k++){
      const float4* wq = (const float4*)(w2 + (size_t)(3*t+k)*Pn);
      float4 q0=wq[0], q1=wq[1], q2=wq[2], q3=wq[3];
      wv[k][0]=q0.x; wv[k][1]=q0.y; wv[k][2]=q0.z; wv[k][3]=q0.w;
      wv[k][4]=q1.x; wv[k][5]=q1.y; wv[k][6]=q1.z; wv[k][7]=q1.w;
      wv[k][8]=q2.x; wv[k][9]=q2.y; wv[k][10]=q2.z; wv[k][11]=q2.w;
      wv[k][12]=q3.x; wv[k][13]=q3.y; wv[k][14]=q3.z; wv[k][15]=q3.w;
    }
    const bool dyn = (mi>=2);
    for(int rr=0; rr<4; ++rr){
      const int r = r0+rr;
      float bv[3];
#pragma unroll
      for(int k=0;k<3;k++)
        bv[k] = (mi==0)? fv[k] : (mi==1)? blv[k] : (mi==2)? aS[rr][k] : aM[rr][k];
      float s0=0.f, sn=0.f;
      float sw[16], snw[16];
#pragma unroll
      for(int p=0;p<16;p++){ sw[p]=0.f; snw[p]=0.f; }
#pragma unroll
      for(int k=0;k<3;k++){
        float pr = v1r[rr][k]*bv[k];
        float bb = bv[k]*bv[k];
        s0 += pr; sn += bb;
#pragma unroll
        for(int p=0;p<16;p++){
          sw[p]=fmaf(wv[k][p],pr,sw[p]);
          if(dyn) snw[p]=fmaf(wv[k][p],bb,snw[p]);
        }
      }
      __syncthreads();    // previous iteration's fin/red readers done
      s0 = wred_sum(s0);
      if(dyn) sn = wred_sum(sn);
#pragma unroll
      for(int p=0;p<16;p++){
        sw[p]=wred_sum(sw[p]);
        if(dyn) snw[p]=wred_sum(snw[p]);
      }
      if(l==0){
        red[0][w]=s0; red[1][w]= dyn? sn : 0.f;
#pragma unroll
        for(int p=0;p<16;p++){ red[2+p][w]=sw[p]; red[18+p][w]= dyn? snw[p] : 0.f; }
      }
      __syncthreads();
      if(t<34) fin[t] = red[t][0]+red[t][1]+red[t][2]+red[t][3];
      __syncthreads();
      float* op = out + ((size_t)((b*2+side)*Ln + r))*Dn;
      if(t==0){
        float nb = dyn ? sqrtf(fmaxf(fin[1],0.f)) : nOther[b*Ln + (mi==0? lpO : 0)];
        float sng = fin[0]/(fmaxf(nv1r[rr],EPSF)*fmaxf(nb,EPSF));
        op[offS[mi]] = sng;
      }
      if(t<16){
        int p=t;
        float wa = fmaxf(wn[wnIdx(side,X,b,p,r)],0.f);
        float wb = dyn ? fmaxf(fin[18+p],0.f) : fmaxf(wn[wnIdx(1-side,X,b,p,(mi==0? lpO:0))],0.f);
        float mul = fin[2+p]/(fmaxf(sqrtf(wa),EPSF)*fmaxf(sqrtf(wb),EPSF));
        op[offS[mi]+1+p] = mul;
      }
    }
  }
}

extern "C" void kernel_launch(void* const* d_in, const int* in_sizes, int n_in,
                              void* d_out, int out_size, void* d_ws, size_t ws_size,
                              hipStream_t stream) {
  const float* ctx1 = (const float*)d_in[0];
  const float* m1   = (const float*)d_in[1];
  const float* ctx2 = (const float*)d_in[2];
  const float* m2   = (const float*)d_in[3];
  const float* wff  = (const float*)d_in[4];
  const float* wfb  = (const float*)d_in[5];
  const float* wmp  = (const float*)d_in[6];
  const float* watt = (const float*)d_in[7];
  const float* wmatt= (const float*)d_in[8];
  float* out = (float*)d_out;
  float* W = (float*)d_ws;
  int* lens = (int*)(W + OFF_LENS);

  k_prep<<<dim3(8 + (5*Pn*Hn)/256), 256, 0, stream>>>(m1,m2,wff,wfb,wmp,watt,wmatt,
      W+OFF_W2T, lens);
  k_rows<<<dim3(Ln,Bn,2), 256, 0, stream>>>(ctx1,m1,ctx2,m2, W+OFF_W2T,
      W+OFF_C1F, W+OFF_C2F, W+OFF_N1, W+OFF_N2, W+OFF_WN);
  k_cos<<<dim3(Bn, Ln/4), 256, 0, stream>>>(W+OFF_C1F, W+OFF_C2F, W+OFF_N1, W+OFF_N2,
      W+OFF_COS, W+OFF_COST);
  k_mm<<<dim3(16, Ln/4), 256, 0, stream>>>(W+OFF_C1F, W+OFF_C2F,
      W+OFF_W2T + (size_t)2*Hn*Pn, W+OFF_WN, m1, m2, lens,
      W+OFF_MVMAX, W+OFF_MVMEAN);
  k_attfin<<<dim3(16, Ln/4), 256, 0, stream>>>(W+OFF_C1F, W+OFF_C2F, W+OFF_COS, W+OFF_COST,
      W+OFF_N1, W+OFF_N2, W+OFF_WN, W+OFF_W2T, W+OFF_MVMAX, W+OFF_MVMEAN,
      lens, m1, m2, out);
}

// Round 5
// 288.152 us; speedup vs baseline: 1.6817x; 1.3251x over previous
//
#include <hip/hip_runtime.h>

#define Bn 8
#define Ln 128
#define Hn 768
#define Pn 16
#define Dn 102
#define EPSF 1e-8f
#define NINF -1e30f

__device__ __forceinline__ float wred_sum(float v){
#pragma unroll
  for(int o=32;o>=1;o>>=1) v += __shfl_xor(v,o);
  return v;
}
__device__ __forceinline__ float wred_max(float v){
#pragma unroll
  for(int o=32;o>=1;o>>=1) v = fmaxf(v,__shfl_xor(v,o));
  return v;
}
// sum over the 4 hq-quarters in the p-in-lane layout (lane = p + 16*hq)
__device__ __forceinline__ float qred_sum(float v){
  v += __shfl_xor(v,16);
  v += __shfl_xor(v,32);
  return v;
}

// ---- workspace layout (float element offsets; total ~12.7 MB) ----
constexpr size_t SZ_MAT   = (size_t)Bn*Ln*Hn;            // 786432
constexpr size_t OFF_C1F  = 0;
constexpr size_t OFF_C2F  = OFF_C1F + SZ_MAT;
constexpr size_t OFF_COS  = OFF_C2F + SZ_MAT;            // B*L*L
constexpr size_t OFF_COST = OFF_COS + (size_t)Bn*Ln*Ln;
constexpr size_t OFF_N1   = OFF_COST + (size_t)Bn*Ln*Ln; // B*L
constexpr size_t OFF_N2   = OFF_N1 + (size_t)Bn*Ln;
constexpr size_t OFF_WN   = OFF_N2 + (size_t)Bn*Ln;      // 2*5*B*P*L
constexpr size_t OFF_W2T  = OFF_WN + (size_t)2*5*Bn*Pn*Ln; // 5*H*P [X][h][p]
constexpr size_t OFF_MVMAX  = OFF_W2T + (size_t)5*Hn*Pn; // 2*B*L*P
constexpr size_t OFF_MVMEAN = OFF_MVMAX + (size_t)2*Bn*Ln*Pn;
constexpr size_t OFF_PART   = OFF_MVMEAN + (size_t)2*Bn*Ln*Pn; // B*L*P*32*2
constexpr size_t OFF_LENS   = OFF_PART + (size_t)Bn*Ln*Pn*32*2; // 32 ints

__device__ __forceinline__ size_t wnIdx(int side,int X,int b,int p,int i){
  return ((((size_t)side*5 + X)*Bn + b)*Pn + p)*Ln + i;
}

// ---------------- k_prep: lengths + squared-weight tables ----------------
__global__ __launch_bounds__(256) void k_prep(
    const float* __restrict__ m1, const float* __restrict__ m2,
    const float* __restrict__ wff, const float* __restrict__ wfb,
    const float* __restrict__ wmp, const float* __restrict__ watt,
    const float* __restrict__ wmatt,
    float* __restrict__ W2T, int* __restrict__ lens){
  int t = threadIdx.x;
  if(blockIdx.x < 8){
    int b = blockIdx.x;
    __shared__ int cnt[2];
    if(t<2) cnt[t]=0;
    __syncthreads();
    if(t<Ln){
      if(m1[b*Ln+t]>0.5f) atomicAdd(&cnt[0],1);
      if(m2[b*Ln+t]>0.5f) atomicAdd(&cnt[1],1);
    }
    __syncthreads();
    if(t==0){
      lens[b]=cnt[0]; lens[8+b]=cnt[1];
      lens[16+b]=max(cnt[0]-1,0); lens[24+b]=max(cnt[1]-1,0);
    }
  } else {
    int idx = (blockIdx.x-8)*256 + t;     // < 5*768*16 = 61440
    const float* srcs[5] = {wff,wfb,wmp,watt,wmatt};
    int X = idx/(Pn*Hn);
    int r = idx%(Pn*Hn);
    int h = r/Pn, p = r%Pn;
    float w = srcs[X][p*Hn+h];
    W2T[idx] = w*w;                        // layout [X][h][p]
  }
}

// ---------------- k_rows: masked rows + norms + weighted norms ----------------
__global__ __launch_bounds__(256) void k_rows(
    const float* __restrict__ ctx1, const float* __restrict__ m1,
    const float* __restrict__ ctx2, const float* __restrict__ m2,
    const float* __restrict__ W2T,
    float* __restrict__ c1f, float* __restrict__ c2f,
    float* __restrict__ n1, float* __restrict__ n2, float* __restrict__ wn){
  int i = blockIdx.x, b = blockIdx.y, side = blockIdx.z;
  const float* ctx = side? ctx2 : ctx1;
  const float* msk = side? m2 : m1;
  float* dst = side? c2f : c1f;
  float* nD  = side? n2 : n1;
  int t = threadIdx.x, w=t>>6, l=t&63;
  float mk = msk[b*Ln+i];
  size_t base = ((size_t)(b*Ln+i))*Hn;
  float v[3];
#pragma unroll
  for(int k=0;k<3;k++){
    float x = ctx[base + t + 256*k] * mk;
    v[k]=x;
    dst[base + t + 256*k] = x;
  }
  __shared__ float red4[4];
  __shared__ float redW[64];
  float ss = v[0]*v[0]+v[1]*v[1]+v[2]*v[2];
  float sst = wred_sum(ss);
  if(l==0) red4[w]=sst;
  __syncthreads();
  if(t==0) nD[b*Ln+i] = sqrtf(fmaxf(red4[0]+red4[1]+red4[2]+red4[3],0.f));
  for(int X=0;X<5;++X){
    float acc[16];
#pragma unroll
    for(int p=0;p<16;p++) acc[p]=0.f;
#pragma unroll
    for(int k=0;k<3;k++){
      int h = t+256*k;
      float vv = v[k]*v[k];
      const float4* wq = (const float4*)(W2T + ((size_t)X*Hn + h)*Pn);
      float4 q0=wq[0],q1=wq[1],q2=wq[2],q3=wq[3];
      float wv[16]={q0.x,q0.y,q0.z,q0.w,q1.x,q1.y,q1.z,q1.w,
                    q2.x,q2.y,q2.z,q2.w,q3.x,q3.y,q3.z,q3.w};
#pragma unroll
      for(int p=0;p<16;p++) acc[p]=fmaf(wv[p],vv,acc[p]);
    }
    __syncthreads();
#pragma unroll
    for(int p=0;p<16;p++){
      float a = wred_sum(acc[p]);
      if(l==0) redW[w*16+p]=a;
    }
    __syncthreads();
    if(t<16){
      float s = redW[t]+redW[16+t]+redW[32+t]+redW[48+t];
      wn[wnIdx(side,X,b,t,i)] = s;
    }
    __syncthreads();
  }
}

// ---------------- k_cos: pairwise cosine; writes cos AND cosT ----------------
// grid (Bn, Ln/2): blockIdx.x = b → XCD-local per batch
__global__ __launch_bounds__(256) void k_cos(
    const float* __restrict__ c1f, const float* __restrict__ c2f,
    const float* __restrict__ n1, const float* __restrict__ n2,
    float* __restrict__ cosM, float* __restrict__ cosTr){
  int b = blockIdx.x, i0 = blockIdx.y*2;
  int t = threadIdx.x, j = t&127, rp = t>>7;
  __shared__ float sA[2*Hn];
  __shared__ float sT[128][2];
  {
    const float4* s4 = (const float4*)(c1f + ((size_t)(b*Ln+i0))*Hn);
    float4* d4 = (float4*)sA;
    for(int idx=t; idx<2*Hn/4; idx+=256) d4[idx]=s4[idx];
  }
  __syncthreads();
  const float4* crow = (const float4*)(c2f + ((size_t)(b*Ln+j))*Hn);
  const float* arow = sA + rp*Hn;
  float a0=0.f;
#pragma unroll 4
  for(int hq=0; hq<Hn/4; ++hq){
    float4 v = crow[hq];
    int h = hq*4;
    a0 = fmaf(arow[h  ], v.x, a0);
    a0 = fmaf(arow[h+1], v.y, a0);
    a0 = fmaf(arow[h+2], v.z, a0);
    a0 = fmaf(arow[h+3], v.w, a0);
  }
  float nj = fmaxf(n2[b*Ln+j], EPSF);
  float va = a0 / (fmaxf(n1[b*Ln+i0+rp],EPSF)*nj);
  cosM[((size_t)(b*Ln+i0+rp))*Ln + j] = va;
  sT[j][rp]=va;
  __syncthreads();
  if(t<128){
    float2 o = *(const float2*)sT[t];
    *((float2*)(cosTr + ((size_t)(b*Ln+t))*Ln + i0)) = o;
  }
}

// ---------------- k_mm: e-tensor ONCE; side0 reduced in-block, side1 partials ----------------
// grid (Bn, Ln/4): rows = c1 (i-tile), lanes = c2 (all j). XCD = b.
__global__ __launch_bounds__(256) void k_mm(
    const float* __restrict__ c1f, const float* __restrict__ c2f,
    const float* __restrict__ W2mp, const float* __restrict__ WN,
    const float* __restrict__ m1, const float* __restrict__ m2,
    const int* __restrict__ lens,
    float* __restrict__ mvmax, float* __restrict__ mvmean,
    float* __restrict__ part){
  const int b = blockIdx.x;
  const int i0 = blockIdx.y*4;
  const int t = threadIdx.x;
  int len2 = min(max(lens[8+b],1),Ln);

  __shared__ float sW2[Hn*Pn];     // 48 KB
  __shared__ float sA[4*Hn];       // 12 KB
  __shared__ float redR[4][4][8][2];
  for(int idx=t; idx<Hn*Pn; idx+=256) sW2[idx]=W2mp[idx];
  for(int idx=t; idx<4*Hn;  idx+=256) sA[idx]=c1f[((size_t)(b*Ln+i0))*Hn + idx];
  __syncthreads();

  const int j = t&127, ph = t>>7;   // ph: p-half (wave-uniform)
  const float4* lrow4 = (const float4*)(c2f + ((size_t)(b*Ln+j))*Hn);
  float acc[4][8];
#pragma unroll
  for(int i=0;i<4;i++)
#pragma unroll
    for(int pp=0;pp<8;pp++) acc[i][pp]=0.f;

#pragma unroll 2
  for(int hq=0; hq<Hn/4; ++hq){
    float4 bq = lrow4[hq];
    int h4 = hq*4;
#pragma unroll
    for(int d=0; d<4; ++d){
      int h = h4+d;
      float bv = (d==0)? bq.x : (d==1)? bq.y : (d==2)? bq.z : bq.w;
      const float4* wrow = (const float4*)(sW2 + h*Pn + ph*8);
      float4 w0 = wrow[0], w1 = wrow[1];
      float wvv[8] = {w0.x,w0.y,w0.z,w0.w,w1.x,w1.y,w1.z,w1.w};
#pragma unroll
      for(int i=0;i<4;i++){
        float pr = sA[i*Hn+h]*bv;
#pragma unroll
        for(int pp=0;pp<8;pp++) acc[i][pp]=fmaf(wvv[pp],pr,acc[i][pp]);
      }
    }
  }

  // normalize in place: acc = e/(sqrt(wn_i)*sqrt(wn_j))
  float slane[8];
#pragma unroll
  for(int pp=0;pp<8;pp++)
    slane[pp] = sqrtf(fmaxf(WN[wnIdx(1,2,b,ph*8+pp,j)],0.f));
#pragma unroll
  for(int i=0;i<4;i++){
#pragma unroll
    for(int pp=0;pp<8;pp++){
      float sr = sqrtf(fmaxf(WN[wnIdx(0,2,b,ph*8+pp,i0+i)],0.f));
      acc[i][pp] = acc[i][pp]/fmaxf(sr*slane[pp],EPSF);
    }
  }

  // ---- side1 partials: reduce over this block's 4 i's (registers only) ----
  {
    float mr[4];
#pragma unroll
    for(int i=0;i<4;i++) mr[i]=m1[b*Ln+i0+i];
    size_t pbase = (((size_t)(b*Ln+j))*Pn + ph*8)*64 + (size_t)blockIdx.y*2;
#pragma unroll
    for(int pp=0;pp<8;pp++){
      float pmax=NINF, psum=0.f;
#pragma unroll
      for(int i=0;i<4;i++){
        if(mr[i]!=0.f){ pmax=fmaxf(pmax,acc[i][pp]); psum+=acc[i][pp]; }
      }
      part[pbase + (size_t)pp*64    ] = pmax;
      part[pbase + (size_t)pp*64 + 1] = psum;
    }
  }

  // ---- side0: full reduction over j (mask2) ----
  const bool valid = (m2[b*Ln+j]!=0.f);
  const int w = t>>6, l = t&63;
#pragma unroll
  for(int i=0;i<4;i++){
#pragma unroll
    for(int pp=0;pp<8;pp++){
      float m = acc[i][pp];
      float vmax = valid? m : NINF;
      float vsum = valid? m : 0.f;
      vmax = wred_max(vmax);
      vsum = wred_sum(vsum);
      if(l==0){ redR[w][i][pp][0]=vmax; redR[w][i][pp][1]=vsum; }
    }
  }
  __syncthreads();
  if(t<128){
    int st = t&1, pp = (t>>1)&7, ii = (t>>4)&3, p2 = (t>>6)&1;
    int p = p2*8+pp;
    float A = redR[2*p2][ii][pp][st], Bv = redR[2*p2+1][ii][pp][st];
    size_t o = ((size_t)(b*Ln + i0+ii))*Pn + p;      // side 0
    if(st==0) mvmax[o] = fmaxf(A,Bv);
    else      mvmean[o] = (A+Bv)/(float)len2;
  }
}

// ---------------- k_mm2: combine side1 partials over 32 i-tiles ----------------
__global__ __launch_bounds__(256) void k_mm2(
    const float* __restrict__ part, const int* __restrict__ lens,
    float* __restrict__ mvmax, float* __restrict__ mvmean){
  int g = blockIdx.x*256 + threadIdx.x;   // 16384 = B*L*P
  int b = g>>11;
  const float4* q = (const float4*)(part + (size_t)g*64);
  float mx = NINF, sm = 0.f;
#pragma unroll
  for(int k=0;k<16;k++){
    float4 v = q[k];
    mx = fmaxf(mx, fmaxf(v.x, v.z));
    sm += v.y + v.w;
  }
  int len1 = min(max(lens[b],1),Ln);
  size_t o = (size_t)Bn*Ln*Pn + g;        // side 1 block of mv arrays
  mvmax[o] = mx;
  mvmean[o] = sm/(float)len1;
}

// ---------------- k_fin: attention + all 102 features; p-in-lane Phase B ----------------
// grid (16, Ln/2): x = side*8+b → XCD = b
__global__ __launch_bounds__(256) void k_fin(
    const float* __restrict__ c1f, const float* __restrict__ c2f,
    const float* __restrict__ cosM, const float* __restrict__ cosTr,
    const float* __restrict__ n1, const float* __restrict__ n2,
    const float* __restrict__ wn, const float* __restrict__ W2T,
    const float* __restrict__ mvmax, const float* __restrict__ mvmean,
    const int* __restrict__ lens,
    const float* __restrict__ m1, const float* __restrict__ m2,
    float* __restrict__ out){
  const int x = blockIdx.x, side = x>>3, b = x&7;
  const int r0 = blockIdx.y*2;
  const int t = threadIdx.x, w = t>>6, l = t&63;
  const float* selfF  = side? c2f : c1f;
  const float* otherF = side? c1f : c2f;
  const float* nSelf  = side? n2 : n1;
  const float* nOther = side? n1 : n2;
  const float* mInner = side? m1 : m2;
  const float* mSelfm = side? m2 : m1;
  int lenI = side? lens[b]    : lens[8+b];
  int lpO  = side? lens[16+b] : lens[24+b];
  lenI = min(max(lenI,1),Ln);
  lpO  = min(max(lpO,0),Ln-1);

  __shared__ float cS[2*Ln];
  __shared__ float mS[Ln];
  __shared__ float sV1[2][Hn];
  __shared__ float sF[Hn], sB[Hn];
  __shared__ float sAS[2][Hn], sAM[2][Hn];
  __shared__ float red[8][4];

  // ---- stage ----
  {
    const float* crow = (side? cosTr : cosM) + ((size_t)(b*Ln+r0))*Ln;
    for(int idx=t; idx<2*Ln; idx+=256) cS[idx]=crow[idx];
    if(t<Ln) mS[t]=mInner[b*Ln+t];
    const float4* s4 = (const float4*)(selfF + ((size_t)(b*Ln+r0))*Hn);
    float4* d4 = (float4*)sV1;
    for(int idx=t; idx<2*Hn/4; idx+=256) d4[idx]=s4[idx];
    const float4* f4 = (const float4*)(otherF + ((size_t)(b*Ln+lpO))*Hn);
    const float4* b4 = (const float4*)(otherF + ((size_t)(b*Ln))*Hn);
    if(t<Hn/4){ ((float4*)sF)[t]=f4[t]; ((float4*)sB)[t]=b4[t]; }
  }
  __syncthreads();

  // ---- attention accumulation (2 rows, h = 3t..3t+2) ----
  float aS0[3]={0,0,0}, aS1[3]={0,0,0}, aM0[3]={NINF,NINF,NINF}, aM1[3]={NINF,NINF,NINF};
  {
    const float* src = otherF + (size_t)b*Ln*Hn;
#pragma unroll 4
    for(int jj=0; jj<Ln; ++jj){
      float3 vk = ((const float3*)(src + (size_t)jj*Hn))[t];
      float msk = mS[jj];
      float c0=cS[jj], c1v=cS[Ln+jj];
      aS0[0]=fmaf(vk.x,c0 ,aS0[0]); aS0[1]=fmaf(vk.y,c0 ,aS0[1]); aS0[2]=fmaf(vk.z,c0 ,aS0[2]);
      aS1[0]=fmaf(vk.x,c1v,aS1[0]); aS1[1]=fmaf(vk.y,c1v,aS1[1]); aS1[2]=fmaf(vk.z,c1v,aS1[2]);
      if(msk!=0.f){
        aM0[0]=fmaxf(aM0[0],vk.x*c0 ); aM0[1]=fmaxf(aM0[1],vk.y*c0 ); aM0[2]=fmaxf(aM0[2],vk.z*c0 );
        aM1[0]=fmaxf(aM1[0],vk.x*c1v); aM1[1]=fmaxf(aM1[1],vk.y*c1v); aM1[2]=fmaxf(aM1[2],vk.z*c1v);
      }
    }
  }

  // ---- softmax over h (2 rows); -1e30 masking => fully-masked rows → uniform ----
  {
    float lm0 = fmaxf(fmaxf(aS0[0],aS0[1]),aS0[2]);
    float lm1 = fmaxf(fmaxf(aS1[0],aS1[1]),aS1[2]);
    lm0 = wred_max(lm0); lm1 = wred_max(lm1);
    if(l==0){ red[0][w]=lm0; red[1][w]=lm1; }
  }
  __syncthreads();
  float bm0 = fmaxf(fmaxf(red[0][0],red[0][1]),fmaxf(red[0][2],red[0][3]));
  float bm1 = fmaxf(fmaxf(red[1][0],red[1][1]),fmaxf(red[1][2],red[1][3]));
  __syncthreads();
  float ev0[3], ev1[3];
  {
    float es0=0.f, es1=0.f;
#pragma unroll
    for(int k=0;k<3;k++){
      ev0[k]=expf(aS0[k]-bm0); es0+=ev0[k];
      ev1[k]=expf(aS1[k]-bm1); es1+=ev1[k];
    }
    es0 = wred_sum(es0); es1 = wred_sum(es1);
    if(l==0){ red[0][w]=es0; red[1][w]=es1; }
  }
  __syncthreads();
  {
    float smr0 = mSelfm[b*Ln+r0], smr1 = mSelfm[b*Ln+r0+1];
    float bs0 = red[0][0]+red[0][1]+red[0][2]+red[0][3];
    float bs1 = red[1][0]+red[1][1]+red[1][2]+red[1][3];
    float inv0 = 1.f/fmaxf(bs0,EPSF), inv1 = 1.f/fmaxf(bs1,EPSF);
    const float u = 1.f/(float)Hn;
#pragma unroll
    for(int k=0;k<3;k++){
      sAS[0][3*t+k] = (smr0!=0.f)? ev0[k]*inv0 : u;
      sAS[1][3*t+k] = (smr1!=0.f)? ev1[k]*inv1 : u;
      sAM[0][3*t+k] = aM0[k];
      sAM[1][3*t+k] = aM1[k];
    }
  }
  __syncthreads();

  // ---- Phase A (waves 0-1) + Phase C (wave 2): independent, no barrier ----
  if(w<2){
    int rr = w;
    float cmx=NINF, csm=0.f;
    float ca = cS[rr*Ln + l], cb = cS[rr*Ln + l + 64];
    if(mS[l]!=0.f){ cmx=ca; csm=ca; }
    if(mS[l+64]!=0.f){ cmx=fmaxf(cmx,cb); csm+=cb; }
    cmx = wred_max(cmx); csm = wred_sum(csm);
    if(l==0){
      float* op = out + ((size_t)((b*2+side)*Ln + r0+rr))*Dn;
      op[0] = cmx;
      op[1] = csm/(float)lenI;
    }
  } else if(w==2){
    int rr = l>>5, qq = l&31, p = qq&15;
    size_t o = ((size_t)((side*Bn+b)*Ln + r0+rr))*Pn + p;
    float* op = out + ((size_t)((b*2+side)*Ln + r0+rr))*Dn;
    if(qq<16) op[36+p] = mvmax[o];
    else      op[52+p] = mvmean[o];
  }

  // ---- Phase B: wave w handles mi=w for both rows; lane = (p, hq) ----
  {
    const int Xids[4] = {0,1,3,4};
    const int offS[4] = {2,19,68,85};
    const int X = Xids[w], offs = offS[w];
    const bool dyn = (w>=2);
    const int p = l&15, hq = l>>4;
    const int h0 = hq*192;
    const float* w2p = W2T + ((size_t)X*Hn)*Pn + p;
    float acc0=0.f, acc1=0.f, s00=0.f, s01=0.f;
    float sn0=0.f, sn1=0.f, sna0=0.f, sna1=0.f;
    if(!dyn){
      const float* bvp = (w==0)? sF : sB;
#pragma unroll 4
      for(int hh=0; hh<192; ++hh){
        int h = h0+hh;
        float w2v = w2p[(size_t)h*Pn];
        float bv = bvp[h];
        float pr0 = sV1[0][h]*bv, pr1 = sV1[1][h]*bv;
        acc0 = fmaf(w2v,pr0,acc0); acc1 = fmaf(w2v,pr1,acc1);
        s00 += pr0; s01 += pr1;
      }
    } else {
      const float* bv0p = (w==2)? sAS[0] : sAM[0];
      const float* bv1p = (w==2)? sAS[1] : sAM[1];
#pragma unroll 4
      for(int hh=0; hh<192; ++hh){
        int h = h0+hh;
        float w2v = w2p[(size_t)h*Pn];
        float bv0 = bv0p[h], bv1 = bv1p[h];
        float pr0 = sV1[0][h]*bv0, pr1 = sV1[1][h]*bv1;
        float bb0 = bv0*bv0, bb1 = bv1*bv1;
        acc0 = fmaf(w2v,pr0,acc0); acc1 = fmaf(w2v,pr1,acc1);
        sna0 = fmaf(w2v,bb0,sna0); sna1 = fmaf(w2v,bb1,sna1);
        s00 += pr0; s01 += pr1;
        sn0 += bb0; sn1 += bb1;
      }
    }
    acc0 = qred_sum(acc0); acc1 = qred_sum(acc1);
    s00  = qred_sum(s00);  s01  = qred_sum(s01);
    if(dyn){
      sna0 = qred_sum(sna0); sna1 = qred_sum(sna1);
      sn0  = qred_sum(sn0);  sn1  = qred_sum(sn1);
    }
    // s00/s01/sn values were computed redundantly by all 16 p-lanes of each
    // quarter; qred sums exactly the 4 distinct quarter-partials. Correct.
#pragma unroll
    for(int rr=0; rr<2; ++rr){
      const int r = r0+rr;
      float accv = rr? acc1 : acc0;
      float s0v  = rr? s01  : s00;
      float snav = rr? sna1 : sna0;
      float snv  = rr? sn1  : sn0;
      float* op = out + ((size_t)((b*2+side)*Ln + r))*Dn;
      if(l<16){
        float wa = fmaxf(wn[wnIdx(side,X,b,l,r)],0.f);
        float wb = dyn? fmaxf(snav,0.f)
                      : fmaxf(wn[wnIdx(1-side,X,b,l,(w==0? lpO:0))],0.f);
        float mul = accv/(fmaxf(sqrtf(wa),EPSF)*fmaxf(sqrtf(wb),EPSF));
        op[offs+1+l] = mul;
      }
      if(l==0){
        float nb = dyn? sqrtf(fmaxf(snv,0.f)) : nOther[b*Ln + (w==0? lpO : 0)];
        float nv1 = nSelf[b*Ln+r];
        op[offs] = s0v/(fmaxf(nv1,EPSF)*fmaxf(nb,EPSF));
      }
    }
  }
}

extern "C" void kernel_launch(void* const* d_in, const int* in_sizes, int n_in,
                              void* d_out, int out_size, void* d_ws, size_t ws_size,
                              hipStream_t stream) {
  const float* ctx1 = (const float*)d_in[0];
  const float* m1   = (const float*)d_in[1];
  const float* ctx2 = (const float*)d_in[2];
  const float* m2   = (const float*)d_in[3];
  const float* wff  = (const float*)d_in[4];
  const float* wfb  = (const float*)d_in[5];
  const float* wmp  = (const float*)d_in[6];
  const float* watt = (const float*)d_in[7];
  const float* wmatt= (const float*)d_in[8];
  float* out = (float*)d_out;
  float* W = (float*)d_ws;
  int* lens = (int*)(W + OFF_LENS);

  k_prep<<<dim3(8 + (5*Pn*Hn)/256), 256, 0, stream>>>(m1,m2,wff,wfb,wmp,watt,wmatt,
      W+OFF_W2T, lens);
  k_rows<<<dim3(Ln,Bn,2), 256, 0, stream>>>(ctx1,m1,ctx2,m2, W+OFF_W2T,
      W+OFF_C1F, W+OFF_C2F, W+OFF_N1, W+OFF_N2, W+OFF_WN);
  k_cos<<<dim3(Bn, Ln/2), 256, 0, stream>>>(W+OFF_C1F, W+OFF_C2F, W+OFF_N1, W+OFF_N2,
      W+OFF_COS, W+OFF_COST);
  k_mm<<<dim3(Bn, Ln/4), 256, 0, stream>>>(W+OFF_C1F, W+OFF_C2F,
      W+OFF_W2T + (size_t)2*Hn*Pn, W+OFF_WN, m1, m2, lens,
      W+OFF_MVMAX, W+OFF_MVMEAN, W+OFF_PART);
  k_mm2<<<dim3((Bn*Ln*Pn)/256), 256, 0, stream>>>(W+OFF_PART, lens,
      W+OFF_MVMAX, W+OFF_MVMEAN);
  k_fin<<<dim3(16, Ln/2), 256, 0, stream>>>(W+OFF_C1F, W+OFF_C2F, W+OFF_COS, W+OFF_COST,
      W+OFF_N1, W+OFF_N2, W+OFF_WN, W+OFF_W2T, W+OFF_MVMAX, W+OFF_MVMEAN,
      lens, m1, m2, out);
}

// Round 6
// 240.655 us; speedup vs baseline: 2.0137x; 1.1974x over previous
//
#include <hip/hip_runtime.h>

#define Bn 8
#define Ln 128
#define Hn 768
#define Pn 16
#define Dn 102
#define EPSF 1e-8f
#define NINF -1e30f

__device__ __forceinline__ float wred_sum(float v){
#pragma unroll
  for(int o=32;o>=1;o>>=1) v += __shfl_xor(v,o);
  return v;
}
__device__ __forceinline__ float wred_max(float v){
#pragma unroll
  for(int o=32;o>=1;o>>=1) v = fmaxf(v,__shfl_xor(v,o));
  return v;
}
// sum over the 4 hq-quarters in the p-in-lane layout (lane = p + 16*hq)
__device__ __forceinline__ float qred_sum(float v){
  v += __shfl_xor(v,16);
  v += __shfl_xor(v,32);
  return v;
}

// ---- workspace layout (float element offsets; total ~12.2 MB) ----
constexpr size_t SZ_MAT   = (size_t)Bn*Ln*Hn;              // 786432
constexpr size_t OFF_C1F  = 0;
constexpr size_t OFF_C2F  = OFF_C1F + SZ_MAT;
constexpr size_t OFF_COS  = OFF_C2F + SZ_MAT;              // B*L*L
constexpr size_t OFF_N1   = OFF_COS + (size_t)Bn*Ln*Ln;    // B*L
constexpr size_t OFF_N2   = OFF_N1 + (size_t)Bn*Ln;
constexpr size_t OFF_WN   = OFF_N2 + (size_t)Bn*Ln;        // 2*5*B*P*L
constexpr size_t OFF_W2T  = OFF_WN + (size_t)2*5*Bn*Pn*Ln; // 5*H*P [X][h][p]
constexpr size_t OFF_MVMAX  = OFF_W2T + (size_t)5*Hn*Pn;   // 2*B*L*P
constexpr size_t OFF_MVMEAN = OFF_MVMAX + (size_t)2*Bn*Ln*Pn;
constexpr size_t OFF_PART   = OFF_MVMEAN + (size_t)2*Bn*Ln*Pn; // B*L*P*32*2
constexpr size_t OFF_LENS   = OFF_PART + (size_t)Bn*Ln*Pn*32*2; // 32 ints

__device__ __forceinline__ size_t wnIdx(int side,int X,int b,int p,int i){
  return ((((size_t)side*5 + X)*Bn + b)*Pn + p)*Ln + i;
}

// ---------------- k_prep: lengths + squared-weight tables ----------------
__global__ __launch_bounds__(256) void k_prep(
    const float* __restrict__ m1, const float* __restrict__ m2,
    const float* __restrict__ wff, const float* __restrict__ wfb,
    const float* __restrict__ wmp, const float* __restrict__ watt,
    const float* __restrict__ wmatt,
    float* __restrict__ W2T, int* __restrict__ lens){
  int t = threadIdx.x;
  if(blockIdx.x < 8){
    int b = blockIdx.x;
    __shared__ int cnt[2];
    if(t<2) cnt[t]=0;
    __syncthreads();
    if(t<Ln){
      if(m1[b*Ln+t]>0.5f) atomicAdd(&cnt[0],1);
      if(m2[b*Ln+t]>0.5f) atomicAdd(&cnt[1],1);
    }
    __syncthreads();
    if(t==0){
      lens[b]=cnt[0]; lens[8+b]=cnt[1];
      lens[16+b]=max(cnt[0]-1,0); lens[24+b]=max(cnt[1]-1,0);
    }
  } else {
    int idx = (blockIdx.x-8)*256 + t;     // < 5*768*16 = 61440
    const float* srcs[5] = {wff,wfb,wmp,watt,wmatt};
    int X = idx/(Pn*Hn);
    int r = idx%(Pn*Hn);
    int h = r/Pn, p = r%Pn;
    float w = srcs[X][p*Hn+h];
    W2T[idx] = w*w;                        // layout [X][h][p]
  }
}

// ---------------- k_rows: masked rows + norms + weighted norms ----------------
__global__ __launch_bounds__(256) void k_rows(
    const float* __restrict__ ctx1, const float* __restrict__ m1,
    const float* __restrict__ ctx2, const float* __restrict__ m2,
    const float* __restrict__ W2T,
    float* __restrict__ c1f, float* __restrict__ c2f,
    float* __restrict__ n1, float* __restrict__ n2, float* __restrict__ wn){
  int i = blockIdx.x, b = blockIdx.y, side = blockIdx.z;
  const float* ctx = side? ctx2 : ctx1;
  const float* msk = side? m2 : m1;
  float* dst = side? c2f : c1f;
  float* nD  = side? n2 : n1;
  int t = threadIdx.x, w=t>>6, l=t&63;
  float mk = msk[b*Ln+i];
  size_t base = ((size_t)(b*Ln+i))*Hn;
  float v[3];
#pragma unroll
  for(int k=0;k<3;k++){
    float x = ctx[base + t + 256*k] * mk;
    v[k]=x;
    dst[base + t + 256*k] = x;
  }
  __shared__ float red4[4];
  __shared__ float redW[64];
  float ss = v[0]*v[0]+v[1]*v[1]+v[2]*v[2];
  float sst = wred_sum(ss);
  if(l==0) red4[w]=sst;
  __syncthreads();
  if(t==0) nD[b*Ln+i] = sqrtf(fmaxf(red4[0]+red4[1]+red4[2]+red4[3],0.f));
  for(int X=0;X<5;++X){
    float acc[16];
#pragma unroll
    for(int p=0;p<16;p++) acc[p]=0.f;
#pragma unroll
    for(int k=0;k<3;k++){
      int h = t+256*k;
      float vv = v[k]*v[k];
      const float4* wq = (const float4*)(W2T + ((size_t)X*Hn + h)*Pn);
      float4 q0=wq[0],q1=wq[1],q2=wq[2],q3=wq[3];
      float wv[16]={q0.x,q0.y,q0.z,q0.w,q1.x,q1.y,q1.z,q1.w,
                    q2.x,q2.y,q2.z,q2.w,q3.x,q3.y,q3.z,q3.w};
#pragma unroll
      for(int p=0;p<16;p++) acc[p]=fmaf(wv[p],vv,acc[p]);
    }
    __syncthreads();
#pragma unroll
    for(int p=0;p<16;p++){
      float a = wred_sum(acc[p]);
      if(l==0) redW[w*16+p]=a;
    }
    __syncthreads();
    if(t<16){
      float s = redW[t]+redW[16+t]+redW[32+t]+redW[48+t];
      wn[wnIdx(side,X,b,t,i)] = s;
    }
    __syncthreads();
  }
}

// ---------------- k_mm: e-tensor + fused cos; side0 in-block, side1 partials ----------------
// grid (Bn, Ln/4), 512 threads = (j:128, ph:2, ih:2). XCD = b.
__global__ __launch_bounds__(512) void k_mm(
    const float* __restrict__ c1f, const float* __restrict__ c2f,
    const float* __restrict__ W2mp, const float* __restrict__ WN,
    const float* __restrict__ n1, const float* __restrict__ n2,
    const float* __restrict__ m1, const float* __restrict__ m2,
    const int* __restrict__ lens,
    float* __restrict__ cosM,
    float* __restrict__ mvmax, float* __restrict__ mvmean,
    float* __restrict__ part){
  const int b = blockIdx.x;
  const int i0 = blockIdx.y*4;
  const int t = threadIdx.x;
  const int j = t&127, ph = (t>>7)&1, ih = t>>8;
  const int phu = __builtin_amdgcn_readfirstlane(ph);   // wave-uniform → SGPR
  const int ihu = __builtin_amdgcn_readfirstlane(ih);

  __shared__ float sA[4*Hn];            // 12 KB
  __shared__ float redR[8][2][8][2];    // 1 KB
  __shared__ float sP[128][16][2];      // 16 KB

  for(int idx=t; idx<4*Hn; idx+=512) sA[idx] = c1f[((size_t)(b*Ln+i0))*Hn + idx];
  __syncthreads();

  const float4* brow = (const float4*)(c2f + ((size_t)(b*Ln+j))*Hn);
  const float4* aR0 = (const float4*)(sA + (2*ihu  )*Hn);
  const float4* aR1 = (const float4*)(sA + (2*ihu+1)*Hn);
  const float* w2b = W2mp + phu*8;      // scalar (s_load) path

  float acc0[8], acc1[8];
#pragma unroll
  for(int pp=0;pp<8;pp++){ acc0[pp]=0.f; acc1[pp]=0.f; }
  float dot0=0.f, dot1=0.f;

#pragma unroll 2
  for(int hq=0; hq<Hn/4; ++hq){
    float4 a0 = aR0[hq];
    float4 a1 = aR1[hq];
    float4 bq = brow[hq];
#pragma unroll
    for(int d=0; d<4; ++d){
      float bv  = (d==0)? bq.x : (d==1)? bq.y : (d==2)? bq.z : bq.w;
      float a0v = (d==0)? a0.x : (d==1)? a0.y : (d==2)? a0.z : a0.w;
      float a1v = (d==0)? a1.x : (d==1)? a1.y : (d==2)? a1.z : a1.w;
      const float* wr = w2b + (size_t)(hq*4+d)*Pn;
      float pr0 = a0v*bv, pr1 = a1v*bv;
      dot0 += pr0; dot1 += pr1;
#pragma unroll
      for(int pp=0;pp<8;pp++){
        float wv = wr[pp];
        acc0[pp]=fmaf(wv,pr0,acc0[pp]);
        acc1[pp]=fmaf(wv,pr1,acc1[pp]);
      }
    }
  }

  const int iA = i0 + 2*ih, iB = iA+1;

  // ---- fused cosine write (ph==0 lanes own it) ----
  if(ph==0){
    float nj = fmaxf(n2[b*Ln+j], EPSF);
    cosM[((size_t)(b*Ln+iA))*Ln + j] = dot0/(fmaxf(n1[b*Ln+iA],EPSF)*nj);
    cosM[((size_t)(b*Ln+iB))*Ln + j] = dot1/(fmaxf(n1[b*Ln+iB],EPSF)*nj);
  }

  // ---- normalize e in place ----
#pragma unroll
  for(int pp=0;pp<8;pp++){
    float sl  = sqrtf(fmaxf(WN[wnIdx(1,2,b,ph*8+pp,j)],0.f));
    float sr0 = sqrtf(fmaxf(WN[wnIdx(0,2,b,ph*8+pp,iA)],0.f));
    float sr1 = sqrtf(fmaxf(WN[wnIdx(0,2,b,ph*8+pp,iB)],0.f));
    acc0[pp] = acc0[pp]/fmaxf(sr0*sl,EPSF);
    acc1[pp] = acc1[pp]/fmaxf(sr1*sl,EPSF);
  }

  // ---- side1 partials: mask over i-rows, combine ih-halves via LDS ----
  {
    float mr0 = m1[b*Ln+iA], mr1 = m1[b*Ln+iB];
    float pmax[8], psum[8];
#pragma unroll
    for(int pp=0;pp<8;pp++){
      float mx=NINF, sm=0.f;
      if(mr0!=0.f){ mx=acc0[pp]; sm=acc0[pp]; }
      if(mr1!=0.f){ mx=fmaxf(mx,acc1[pp]); sm+=acc1[pp]; }
      pmax[pp]=mx; psum[pp]=sm;
    }
    if(ih==0){
#pragma unroll
      for(int pp=0;pp<8;pp++){ sP[j][ph*8+pp][0]=pmax[pp]; sP[j][ph*8+pp][1]=psum[pp]; }
    }
    __syncthreads();
    if(ih==1){
#pragma unroll
      for(int pp=0;pp<8;pp++){
        float M = fmaxf(sP[j][ph*8+pp][0], pmax[pp]);
        float S = sP[j][ph*8+pp][1] + psum[pp];
        size_t o = ((((size_t)(b*Ln+j))*Pn + ph*8+pp)*32 + blockIdx.y)*2;
        part[o]=M; part[o+1]=S;
      }
    }
  }

  // ---- side0: reduce over j (mask2) ----
  {
    const bool valid = (m2[b*Ln+j]!=0.f);
    const int w = t>>6, l = t&63;
#pragma unroll
    for(int r=0;r<2;r++){
#pragma unroll
      for(int pp=0;pp<8;pp++){
        float m = r? acc1[pp] : acc0[pp];
        float vmax = valid? m : NINF;
        float vsum = valid? m : 0.f;
        vmax = wred_max(vmax);
        vsum = wred_sum(vsum);
        if(l==0){ redR[w][r][pp][0]=vmax; redR[w][r][pp][1]=vsum; }
      }
    }
    __syncthreads();
    if(t<128){
      int st=t&1, pp=(t>>1)&7, r=(t>>4)&1, phh=(t>>5)&1, ihh=t>>6;
      int wbase = 4*ihh + 2*phh;
      float A = redR[wbase][r][pp][st], Bv = redR[wbase+1][r][pp][st];
      int iL = 2*ihh + r, p = phh*8+pp;
      int len2 = min(max(lens[8+b],1),Ln);
      size_t o = ((size_t)(b*Ln + i0+iL))*Pn + p;      // side 0
      if(st==0) mvmax[o] = fmaxf(A,Bv);
      else      mvmean[o] = (A+Bv)/(float)len2;
    }
  }
}

// ---------------- k_mm2: combine side1 partials over 32 i-tiles ----------------
__global__ __launch_bounds__(256) void k_mm2(
    const float* __restrict__ part, const int* __restrict__ lens,
    float* __restrict__ mvmax, float* __restrict__ mvmean){
  int g = blockIdx.x*256 + threadIdx.x;   // 16384 = B*L*P
  int b = g>>11;
  const float4* q = (const float4*)(part + (size_t)g*64);
  float mx = NINF, sm = 0.f;
#pragma unroll
  for(int k=0;k<16;k++){
    float4 v = q[k];
    mx = fmaxf(mx, fmaxf(v.x, v.z));
    sm += v.y + v.w;
  }
  int len1 = min(max(lens[b],1),Ln);
  size_t o = (size_t)Bn*Ln*Pn + g;        // side 1 block of mv arrays
  mvmax[o] = mx;
  mvmean[o] = sm/(float)len1;
}

// ---------------- k_fin: attention + all 102 features; p-in-lane Phase B ----------------
// grid (16, Ln/2): x = side*8+b → XCD = b
__global__ __launch_bounds__(256) void k_fin(
    const float* __restrict__ c1f, const float* __restrict__ c2f,
    const float* __restrict__ cosM,
    const float* __restrict__ n1, const float* __restrict__ n2,
    const float* __restrict__ wn, const float* __restrict__ W2T,
    const float* __restrict__ mvmax, const float* __restrict__ mvmean,
    const int* __restrict__ lens,
    const float* __restrict__ m1, const float* __restrict__ m2,
    float* __restrict__ out){
  const int x = blockIdx.x, side = x>>3, b = x&7;
  const int r0 = blockIdx.y*2;
  const int t = threadIdx.x, w = t>>6, l = t&63;
  const float* selfF  = side? c2f : c1f;
  const float* otherF = side? c1f : c2f;
  const float* nSelf  = side? n2 : n1;
  const float* nOther = side? n1 : n2;
  const float* mInner = side? m1 : m2;
  const float* mSelfm = side? m2 : m1;
  int lenI = side? lens[b]    : lens[8+b];
  int lpO  = side? lens[16+b] : lens[24+b];
  lenI = min(max(lenI,1),Ln);
  lpO  = min(max(lpO,0),Ln-1);

  __shared__ float cS[2*Ln];
  __shared__ float mS[Ln];
  __shared__ float sV1[2][Hn];
  __shared__ float sF[Hn], sB[Hn];
  __shared__ float sAS[2][Hn], sAM[2][Hn];
  __shared__ float red[8][4];

  // ---- stage ----
  {
    if(side==0){
      const float* crow = cosM + ((size_t)(b*Ln+r0))*Ln;
      for(int idx=t; idx<2*Ln; idx+=256) cS[idx]=crow[idx];
    } else {
      int jj = t&127, rp = t>>7;   // transposed read: cos^T[r][j] = cosM[j][r]
      cS[rp*Ln+jj] = cosM[((size_t)(b*Ln+jj))*Ln + r0+rp];
    }
    if(t<Ln) mS[t]=mInner[b*Ln+t];
    const float4* s4 = (const float4*)(selfF + ((size_t)(b*Ln+r0))*Hn);
    float4* d4 = (float4*)sV1;
    for(int idx=t; idx<2*Hn/4; idx+=256) d4[idx]=s4[idx];
    const float4* f4 = (const float4*)(otherF + ((size_t)(b*Ln+lpO))*Hn);
    const float4* b4 = (const float4*)(otherF + ((size_t)(b*Ln))*Hn);
    if(t<Hn/4){ ((float4*)sF)[t]=f4[t]; ((float4*)sB)[t]=b4[t]; }
  }
  __syncthreads();

  // ---- attention accumulation (2 rows, h = 3t..3t+2) ----
  float aS0[3]={0,0,0}, aS1[3]={0,0,0}, aM0[3]={NINF,NINF,NINF}, aM1[3]={NINF,NINF,NINF};
  {
    const float* src = otherF + (size_t)b*Ln*Hn;
#pragma unroll 4
    for(int jj=0; jj<Ln; ++jj){
      float3 vk = ((const float3*)(src + (size_t)jj*Hn))[t];
      float msk = mS[jj];
      float c0=cS[jj], c1v=cS[Ln+jj];
      aS0[0]=fmaf(vk.x,c0 ,aS0[0]); aS0[1]=fmaf(vk.y,c0 ,aS0[1]); aS0[2]=fmaf(vk.z,c0 ,aS0[2]);
      aS1[0]=fmaf(vk.x,c1v,aS1[0]); aS1[1]=fmaf(vk.y,c1v,aS1[1]); aS1[2]=fmaf(vk.z,c1v,aS1[2]);
      if(msk!=0.f){
        aM0[0]=fmaxf(aM0[0],vk.x*c0 ); aM0[1]=fmaxf(aM0[1],vk.y*c0 ); aM0[2]=fmaxf(aM0[2],vk.z*c0 );
        aM1[0]=fmaxf(aM1[0],vk.x*c1v); aM1[1]=fmaxf(aM1[1],vk.y*c1v); aM1[2]=fmaxf(aM1[2],vk.z*c1v);
      }
    }
  }

  // ---- softmax over h (2 rows); -1e30 masking => fully-masked rows → uniform ----
  {
    float lm0 = fmaxf(fmaxf(aS0[0],aS0[1]),aS0[2]);
    float lm1 = fmaxf(fmaxf(aS1[0],aS1[1]),aS1[2]);
    lm0 = wred_max(lm0); lm1 = wred_max(lm1);
    if(l==0){ red[0][w]=lm0; red[1][w]=lm1; }
  }
  __syncthreads();
  float bm0 = fmaxf(fmaxf(red[0][0],red[0][1]),fmaxf(red[0][2],red[0][3]));
  float bm1 = fmaxf(fmaxf(red[1][0],red[1][1]),fmaxf(red[1][2],red[1][3]));
  __syncthreads();
  float ev0[3], ev1[3];
  {
    float es0=0.f, es1=0.f;
#pragma unroll
    for(int k=0;k<3;k++){
      ev0[k]=expf(aS0[k]-bm0); es0+=ev0[k];
      ev1[k]=expf(aS1[k]-bm1); es1+=ev1[k];
    }
    es0 = wred_sum(es0); es1 = wred_sum(es1);
    if(l==0){ red[0][w]=es0; red[1][w]=es1; }
  }
  __syncthreads();
  {
    float smr0 = mSelfm[b*Ln+r0], smr1 = mSelfm[b*Ln+r0+1];
    float bs0 = red[0][0]+red[0][1]+red[0][2]+red[0][3];
    float bs1 = red[1][0]+red[1][1]+red[1][2]+red[1][3];
    float inv0 = 1.f/fmaxf(bs0,EPSF), inv1 = 1.f/fmaxf(bs1,EPSF);
    const float u = 1.f/(float)Hn;
#pragma unroll
    for(int k=0;k<3;k++){
      sAS[0][3*t+k] = (smr0!=0.f)? ev0[k]*inv0 : u;
      sAS[1][3*t+k] = (smr1!=0.f)? ev1[k]*inv1 : u;
      sAM[0][3*t+k] = aM0[k];
      sAM[1][3*t+k] = aM1[k];
    }
  }
  __syncthreads();

  // ---- Phase A (waves 0-1) + Phase C (wave 2): independent, no barrier ----
  if(w<2){
    int rr = w;
    float cmx=NINF, csm=0.f;
    float ca = cS[rr*Ln + l], cb = cS[rr*Ln + l + 64];
    if(mS[l]!=0.f){ cmx=ca; csm=ca; }
    if(mS[l+64]!=0.f){ cmx=fmaxf(cmx,cb); csm+=cb; }
    cmx = wred_max(cmx); csm = wred_sum(csm);
    if(l==0){
      float* op = out + ((size_t)((b*2+side)*Ln + r0+rr))*Dn;
      op[0] = cmx;
      op[1] = csm/(float)lenI;
    }
  } else if(w==2){
    int rr = l>>5, qq = l&31, p = qq&15;
    size_t o = ((size_t)((side*Bn+b)*Ln + r0+rr))*Pn + p;
    float* op = out + ((size_t)((b*2+side)*Ln + r0+rr))*Dn;
    if(qq<16) op[36+p] = mvmax[o];
    else      op[52+p] = mvmean[o];
  }

  // ---- Phase B: wave w handles mi=w for both rows; lane = (p, hq) ----
  {
    const int Xids[4] = {0,1,3,4};
    const int offS[4] = {2,19,68,85};
    const int X = Xids[w], offs = offS[w];
    const bool dyn = (w>=2);
    const int p = l&15, hq = l>>4;
    const int h0 = hq*192;
    const float* w2p = W2T + ((size_t)X*Hn)*Pn + p;
    float acc0=0.f, acc1=0.f, s00=0.f, s01=0.f;
    float sn0=0.f, sn1=0.f, sna0=0.f, sna1=0.f;
    if(!dyn){
      const float* bvp = (w==0)? sF : sB;
#pragma unroll 4
      for(int hh=0; hh<192; ++hh){
        int h = h0+hh;
        float w2v = w2p[(size_t)h*Pn];
        float bv = bvp[h];
        float pr0 = sV1[0][h]*bv, pr1 = sV1[1][h]*bv;
        acc0 = fmaf(w2v,pr0,acc0); acc1 = fmaf(w2v,pr1,acc1);
        s00 += pr0; s01 += pr1;
      }
    } else {
      const float* bv0p = (w==2)? sAS[0] : sAM[0];
      const float* bv1p = (w==2)? sAS[1] : sAM[1];
#pragma unroll 4
      for(int hh=0; hh<192; ++hh){
        int h = h0+hh;
        float w2v = w2p[(size_t)h*Pn];
        float bv0 = bv0p[h], bv1 = bv1p[h];
        float pr0 = sV1[0][h]*bv0, pr1 = sV1[1][h]*bv1;
        float bb0 = bv0*bv0, bb1 = bv1*bv1;
        acc0 = fmaf(w2v,pr0,acc0); acc1 = fmaf(w2v,pr1,acc1);
        sna0 = fmaf(w2v,bb0,sna0); sna1 = fmaf(w2v,bb1,sna1);
        s00 += pr0; s01 += pr1;
        sn0 += bb0; sn1 += bb1;
      }
    }
    acc0 = qred_sum(acc0); acc1 = qred_sum(acc1);
    s00  = qred_sum(s00);  s01  = qred_sum(s01);
    if(dyn){
      sna0 = qred_sum(sna0); sna1 = qred_sum(sna1);
      sn0  = qred_sum(sn0);  sn1  = qred_sum(sn1);
    }
#pragma unroll
    for(int rr=0; rr<2; ++rr){
      const int r = r0+rr;
      float accv = rr? acc1 : acc0;
      float s0v  = rr? s01  : s00;
      float snav = rr? sna1 : sna0;
      float snv  = rr? sn1  : sn0;
      float* op = out + ((size_t)((b*2+side)*Ln + r))*Dn;
      if(l<16){
        float wa = fmaxf(wn[wnIdx(side,X,b,l,r)],0.f);
        float wb = dyn? fmaxf(snav,0.f)
                      : fmaxf(wn[wnIdx(1-side,X,b,l,(w==0? lpO:0))],0.f);
        float mul = accv/(fmaxf(sqrtf(wa),EPSF)*fmaxf(sqrtf(wb),EPSF));
        op[offs+1+l] = mul;
      }
      if(l==0){
        float nb = dyn? sqrtf(fmaxf(snv,0.f)) : nOther[b*Ln + (w==0? lpO : 0)];
        float nv1 = nSelf[b*Ln+r];
        op[offs] = s0v/(fmaxf(nv1,EPSF)*fmaxf(nb,EPSF));
      }
    }
  }
}

extern "C" void kernel_launch(void* const* d_in, const int* in_sizes, int n_in,
                              void* d_out, int out_size, void* d_ws, size_t ws_size,
                              hipStream_t stream) {
  const float* ctx1 = (const float*)d_in[0];
  const float* m1   = (const float*)d_in[1];
  const float* ctx2 = (const float*)d_in[2];
  const float* m2   = (const float*)d_in[3];
  const float* wff  = (const float*)d_in[4];
  const float* wfb  = (const float*)d_in[5];
  const float* wmp  = (const float*)d_in[6];
  const float* watt = (const float*)d_in[7];
  const float* wmatt= (const float*)d_in[8];
  float* out = (float*)d_out;
  float* W = (float*)d_ws;
  int* lens = (int*)(W + OFF_LENS);

  k_prep<<<dim3(8 + (5*Pn*Hn)/256), 256, 0, stream>>>(m1,m2,wff,wfb,wmp,watt,wmatt,
      W+OFF_W2T, lens);
  k_rows<<<dim3(Ln,Bn,2), 256, 0, stream>>>(ctx1,m1,ctx2,m2, W+OFF_W2T,
      W+OFF_C1F, W+OFF_C2F, W+OFF_N1, W+OFF_N2, W+OFF_WN);
  k_mm<<<dim3(Bn, Ln/4), 512, 0, stream>>>(W+OFF_C1F, W+OFF_C2F,
      W+OFF_W2T + (size_t)2*Hn*Pn, W+OFF_WN, W+OFF_N1, W+OFF_N2,
      m1, m2, lens, W+OFF_COS,
      W+OFF_MVMAX, W+OFF_MVMEAN, W+OFF_PART);
  k_mm2<<<dim3((Bn*Ln*Pn)/256), 256, 0, stream>>>(W+OFF_PART, lens,
      W+OFF_MVMAX, W+OFF_MVMEAN);
  k_fin<<<dim3(16, Ln/2), 256, 0, stream>>>(W+OFF_C1F, W+OFF_C2F, W+OFF_COS,
      W+OFF_N1, W+OFF_N2, W+OFF_WN, W+OFF_W2T, W+OFF_MVMAX, W+OFF_MVMEAN,
      lens, m1, m2, out);
}